// Round 1
// baseline (5190.207 us; speedup 1.0000x reference)
//
#include <hip/hip_runtime.h>
#include <math.h>

#define T_SEQ   1024
#define BATCH   8
#define DMODEL  512
#define DINNER  1024
#define DSTATE  16
#define DTRANK  32
#define NLAYER  4
#define MROWS   (BATCH * T_SEQ)   // 8192

// ---------------- generic tiled fp32 GEMM ----------------
// C[M,N] = A[M,K](lda) @ B[K,N](ldb=N)  with epilogues:
// EPI 0: none; 1: +bias[n]; 2: softplus(x + bias[n]); 3: C += acc (residual, in-place)
#define BM 64
#define BN 64
#define BK 16

template<int EPI>
__global__ __launch_bounds__(256)
void gemm_f32(const float* __restrict__ A, int lda,
              const float* __restrict__ B,
              const float* __restrict__ bias,
              float* __restrict__ C, int ldc,
              int M, int N, int K)
{
    __shared__ float As[BK][BM];
    __shared__ float Bs[BK][BN];
    const int bn = blockIdx.x * BN;
    const int bm = blockIdx.y * BM;
    const int tid = threadIdx.x;
    const int tx = tid & 15;          // n-direction
    const int ty = tid >> 4;          // m-direction
    const int ar = tid >> 2;          // 0..63  (A tile row)
    const int ac = (tid & 3) * 4;     // 0,4,8,12 (A tile col)
    const int br = tid >> 4;          // 0..15  (B tile row)
    const int bc = (tid & 15) * 4;    // B tile col

    float acc[4][4] = {};

    for (int k0 = 0; k0 < K; k0 += BK) {
        float4 av = *(const float4*)&A[(bm + ar) * lda + k0 + ac];
        float4 bv = *(const float4*)&B[(k0 + br) * N + bn + bc];
        As[ac + 0][ar] = av.x;
        As[ac + 1][ar] = av.y;
        As[ac + 2][ar] = av.z;
        As[ac + 3][ar] = av.w;
        *(float4*)&Bs[br][bc] = bv;
        __syncthreads();
        #pragma unroll
        for (int kk = 0; kk < BK; ++kk) {
            float4 a = *(const float4*)&As[kk][ty * 4];
            float4 b = *(const float4*)&Bs[kk][tx * 4];
            float af[4] = {a.x, a.y, a.z, a.w};
            float bf[4] = {b.x, b.y, b.z, b.w};
            #pragma unroll
            for (int i = 0; i < 4; ++i)
                #pragma unroll
                for (int j = 0; j < 4; ++j)
                    acc[i][j] = fmaf(af[i], bf[j], acc[i][j]);
        }
        __syncthreads();
    }

    #pragma unroll
    for (int i = 0; i < 4; ++i) {
        int r = bm + ty * 4 + i;
        float* cp = &C[r * ldc + bn + tx * 4];
        float v[4];
        #pragma unroll
        for (int j = 0; j < 4; ++j) {
            float xv = acc[i][j];
            if (EPI == 1) xv += bias[bn + tx * 4 + j];
            if (EPI == 2) {
                xv += bias[bn + tx * 4 + j];
                xv = (xv > 20.f) ? xv : log1pf(__expf(xv));
            }
            v[j] = xv;
        }
        if (EPI == 3) {
            float4 old = *(const float4*)cp;
            v[0] += old.x; v[1] += old.y; v[2] += old.z; v[3] += old.w;
        }
        float4 o; o.x = v[0]; o.y = v[1]; o.z = v[2]; o.w = v[3];
        *(float4*)cp = o;
    }
}

// ---------------- LayerNorm over last dim (512) ----------------
__global__ __launch_bounds__(256)
void ln_kernel(const float* __restrict__ x, const float* __restrict__ w,
               const float* __restrict__ b, float* __restrict__ out)
{
    int row = blockIdx.x;
    const float* xr = x + (size_t)row * DMODEL;
    int tid = threadIdx.x;
    float2 v = ((const float2*)xr)[tid];
    float s  = v.x + v.y;
    float sq = v.x * v.x + v.y * v.y;
    #pragma unroll
    for (int off = 32; off > 0; off >>= 1) {
        s  += __shfl_down(s, off);
        sq += __shfl_down(sq, off);
    }
    __shared__ float ss[4], ssq[4];
    if ((tid & 63) == 0) { ss[tid >> 6] = s; ssq[tid >> 6] = sq; }
    __syncthreads();
    s  = ss[0] + ss[1] + ss[2] + ss[3];
    sq = ssq[0] + ssq[1] + ssq[2] + ssq[3];
    float mu  = s * (1.f / DMODEL);
    float var = sq * (1.f / DMODEL) - mu * mu;
    float rs  = rsqrtf(var + 1e-5f);
    float2 wv = ((const float2*)w)[tid];
    float2 bv = ((const float2*)b)[tid];
    float2 o;
    o.x = (v.x - mu) * rs * wv.x + bv.x;
    o.y = (v.y - mu) * rs * wv.y + bv.y;
    ((float2*)(out + (size_t)row * DMODEL))[tid] = o;
}

// ---------------- depthwise causal conv(3) + silu ----------------
__global__ __launch_bounds__(256)
void conv_silu(const float* __restrict__ xz, const float* __restrict__ cw,
               const float* __restrict__ cb, float* __restrict__ u)
{
    int idx = blockIdx.x * 256 + threadIdx.x;   // < MROWS * DINNER
    int d   = idx & (DINNER - 1);
    int row = idx >> 10;
    int t   = row & (T_SEQ - 1);
    float acc = cb[d];
    #pragma unroll
    for (int k = 0; k < 3; ++k) {
        int tt = t - 2 + k;
        if (tt >= 0)
            acc += xz[(size_t)(row - 2 + k) * (2 * DINNER) + d] * cw[d * 3 + k];
    }
    u[(size_t)row * DINNER + d] = acc / (1.f + __expf(-acc));
}

// ---------------- selective scan + fused epilogue ----------------
__global__ __launch_bounds__(256)
void scan_kernel(const float* __restrict__ delta, const float* __restrict__ u,
                 const float* __restrict__ xdbl, const float* __restrict__ A_log,
                 const float* __restrict__ Dp, const float* __restrict__ xz,
                 float* __restrict__ yy)
{
    int tid = threadIdx.x;
    int s    = tid & 15;
    int cloc = tid >> 4;                    // 0..15
    int ch   = blockIdx.x * 16 + cloc;      // 0..8191
    int b = ch >> 10;
    int d = ch & (DINNER - 1);
    float Aval = -__expf(A_log[d * DSTATE + s]);
    float Dval = Dp[d];
    float h = 0.f;
    int rowbase = b * T_SEQ;
    for (int t = 0; t < T_SEQ; ++t) {
        int row = rowbase + t;
        float dlt = delta[(size_t)row * DINNER + d];
        float ut  = u[(size_t)row * DINNER + d];
        float Bv  = xdbl[(size_t)row * 64 + DTRANK + s];
        float Cv  = xdbl[(size_t)row * 64 + DTRANK + DSTATE + s];
        float e = __expf(dlt * Aval);
        h = e * h + (dlt * ut) * Bv;
        float p = h * Cv;
        p += __shfl_xor(p, 1);
        p += __shfl_xor(p, 2);
        p += __shfl_xor(p, 4);
        p += __shfl_xor(p, 8);
        if (s == 0) {
            float z = xz[(size_t)row * (2 * DINNER) + DINNER + d];
            float sil = z / (1.f + __expf(-z));
            yy[(size_t)row * DINNER + d] = (p + Dval * ut) * sil;
        }
    }
}

// ---------------- masked mean pool ----------------
__global__ __launch_bounds__(512)
void pool_kernel(const float* __restrict__ h, const int* __restrict__ lengths,
                 float* __restrict__ pooled)
{
    int b  = blockIdx.x;
    int dm = threadIdx.x;   // 512
    int len = lengths[b];
    float cnt = fmaxf((float)len, 1.f);
    float acc = 0.f;
    for (int t = 0; t < len; ++t)
        acc += h[((size_t)b * T_SEQ + t) * DMODEL + dm];
    pooled[b * DMODEL + dm] = acc / cnt;
}

extern "C" void kernel_launch(void* const* d_in, const int* in_sizes, int n_in,
                              void* d_out, int out_size, void* d_ws, size_t ws_size,
                              hipStream_t stream)
{
    const float* x        = (const float*)d_in[0];
    const int*   lengths  = (const int*)d_in[1];
    const float* proj_w   = (const float*)d_in[2];
    const float* proj_b   = (const float*)d_in[3];
    const float* ln_w     = (const float*)d_in[4];
    const float* ln_b     = (const float*)d_in[5];
    const float* in_w     = (const float*)d_in[6];
    const float* conv_w   = (const float*)d_in[7];
    const float* conv_b   = (const float*)d_in[8];
    const float* xproj_w  = (const float*)d_in[9];
    const float* dtproj_w = (const float*)d_in[10];
    const float* dtproj_b = (const float*)d_in[11];
    const float* A_log    = (const float*)d_in[12];
    const float* Dp       = (const float*)d_in[13];
    const float* out_w    = (const float*)d_in[14];

    float* h      = (float*)d_out;                 // seq_out lives here (8192x512)
    float* pooled = h + (size_t)MROWS * DMODEL;

    float* ws    = (float*)d_ws;
    float* h_ln  = ws;                                    // 8192*512
    float* xz    = h_ln + (size_t)MROWS * DMODEL;         // 8192*2048
    float* u     = xz   + (size_t)MROWS * 2 * DINNER;     // 8192*1024
    float* xdbl  = u    + (size_t)MROWS * DINNER;         // 8192*64
    float* delta = xdbl + (size_t)MROWS * 64;             // 8192*1024 (also yy)

    // h = x @ proj_w + proj_b   (M=8192, K=80, N=512)
    gemm_f32<1><<<dim3(DMODEL / BN, MROWS / BM), 256, 0, stream>>>(
        x, 80, proj_w, proj_b, h, DMODEL, MROWS, DMODEL, 80);

    for (int l = 0; l < NLAYER; ++l) {
        ln_kernel<<<MROWS, 256, 0, stream>>>(h, ln_w + l * DMODEL, ln_b + l * DMODEL, h_ln);

        // xz = h_ln @ in_w   (K=512, N=2048)
        gemm_f32<0><<<dim3(2 * DINNER / BN, MROWS / BM), 256, 0, stream>>>(
            h_ln, DMODEL, in_w + (size_t)l * DMODEL * 2 * DINNER, nullptr,
            xz, 2 * DINNER, MROWS, 2 * DINNER, DMODEL);

        conv_silu<<<(MROWS * DINNER) / 256, 256, 0, stream>>>(
            xz, conv_w + l * DINNER * 3, conv_b + l * DINNER, u);

        // x_dbl = u @ xproj_w   (K=1024, N=64)
        gemm_f32<0><<<dim3(64 / BN, MROWS / BM), 256, 0, stream>>>(
            u, DINNER, xproj_w + (size_t)l * DINNER * 64, nullptr,
            xdbl, 64, MROWS, 64, DINNER);

        // delta = softplus(dt @ dtproj_w + dtproj_b)   (K=32, N=1024), dt = xdbl[:, :32]
        gemm_f32<2><<<dim3(DINNER / BN, MROWS / BM), 256, 0, stream>>>(
            xdbl, 64, dtproj_w + (size_t)l * DTRANK * DINNER, dtproj_b + l * DINNER,
            delta, DINNER, MROWS, DINNER, DTRANK);

        // selective scan + (y + D*u)*silu(z) -> yy (aliases delta)
        scan_kernel<<<(BATCH * DINNER) / 16, 256, 0, stream>>>(
            delta, u, xdbl, A_log + (size_t)l * DINNER * DSTATE, Dp + l * DINNER,
            xz, delta);

        // h += yy @ out_w   (K=1024, N=512)
        gemm_f32<3><<<dim3(DMODEL / BN, MROWS / BM), 256, 0, stream>>>(
            delta, DINNER, out_w + (size_t)l * DINNER * DMODEL, nullptr,
            h, DMODEL, MROWS, DMODEL, DINNER);
    }

    pool_kernel<<<BATCH, DMODEL, 0, stream>>>(h, lengths, pooled);
}

// Round 2
// 3175.098 us; speedup vs baseline: 1.6347x; 1.6347x over previous
//
#include <hip/hip_runtime.h>
#include <math.h>

#define T_SEQ   1024
#define BATCH   8
#define DMODEL  512
#define DINNER  1024
#define DSTATE  16
#define DTRANK  32
#define NLAYER  4
#define MROWS   (BATCH * T_SEQ)   // 8192
#define NCH     8                 // scan chunks
#define CLEN    (T_SEQ / NCH)     // 128
#define NCHAN   (BATCH * DINNER)  // 8192 channels

// ---------------- generic tiled fp32 GEMM ----------------
// C[M,N] = A[M,K](lda) @ B[K,N](ldb=N)  with epilogues:
// EPI 0: none; 1: +bias[n]; 2: softplus(x + bias[n]); 3: C += acc (residual, in-place)
#define BM 64
#define BN 64
#define BK 16

template<int EPI>
__global__ __launch_bounds__(256)
void gemm_f32(const float* __restrict__ A, int lda,
              const float* __restrict__ B,
              const float* __restrict__ bias,
              float* __restrict__ C, int ldc,
              int M, int N, int K)
{
    __shared__ float As[BK][BM];
    __shared__ float Bs[BK][BN];
    const int bn = blockIdx.x * BN;
    const int bm = blockIdx.y * BM;
    const int tid = threadIdx.x;
    const int tx = tid & 15;          // n-direction
    const int ty = tid >> 4;          // m-direction
    const int ar = tid >> 2;          // 0..63  (A tile row)
    const int ac = (tid & 3) * 4;     // 0,4,8,12 (A tile col)
    const int br = tid >> 4;          // 0..15  (B tile row)
    const int bc = (tid & 15) * 4;    // B tile col

    float acc[4][4] = {};

    for (int k0 = 0; k0 < K; k0 += BK) {
        float4 av = *(const float4*)&A[(bm + ar) * lda + k0 + ac];
        float4 bv = *(const float4*)&B[(k0 + br) * N + bn + bc];
        As[ac + 0][ar] = av.x;
        As[ac + 1][ar] = av.y;
        As[ac + 2][ar] = av.z;
        As[ac + 3][ar] = av.w;
        *(float4*)&Bs[br][bc] = bv;
        __syncthreads();
        #pragma unroll
        for (int kk = 0; kk < BK; ++kk) {
            float4 a = *(const float4*)&As[kk][ty * 4];
            float4 b = *(const float4*)&Bs[kk][tx * 4];
            float af[4] = {a.x, a.y, a.z, a.w};
            float bf[4] = {b.x, b.y, b.z, b.w};
            #pragma unroll
            for (int i = 0; i < 4; ++i)
                #pragma unroll
                for (int j = 0; j < 4; ++j)
                    acc[i][j] = fmaf(af[i], bf[j], acc[i][j]);
        }
        __syncthreads();
    }

    #pragma unroll
    for (int i = 0; i < 4; ++i) {
        int r = bm + ty * 4 + i;
        float* cp = &C[r * ldc + bn + tx * 4];
        float v[4];
        #pragma unroll
        for (int j = 0; j < 4; ++j) {
            float xv = acc[i][j];
            if (EPI == 1) xv += bias[bn + tx * 4 + j];
            if (EPI == 2) {
                xv += bias[bn + tx * 4 + j];
                xv = (xv > 20.f) ? xv : log1pf(__expf(xv));
            }
            v[j] = xv;
        }
        if (EPI == 3) {
            float4 old = *(const float4*)cp;
            v[0] += old.x; v[1] += old.y; v[2] += old.z; v[3] += old.w;
        }
        float4 o; o.x = v[0]; o.y = v[1]; o.z = v[2]; o.w = v[3];
        *(float4*)cp = o;
    }
}

// ---------------- LayerNorm over last dim (512) ----------------
__global__ __launch_bounds__(256)
void ln_kernel(const float* __restrict__ x, const float* __restrict__ w,
               const float* __restrict__ b, float* __restrict__ out)
{
    int row = blockIdx.x;
    const float* xr = x + (size_t)row * DMODEL;
    int tid = threadIdx.x;
    float2 v = ((const float2*)xr)[tid];
    float s  = v.x + v.y;
    float sq = v.x * v.x + v.y * v.y;
    #pragma unroll
    for (int off = 32; off > 0; off >>= 1) {
        s  += __shfl_down(s, off);
        sq += __shfl_down(sq, off);
    }
    __shared__ float ss[4], ssq[4];
    if ((tid & 63) == 0) { ss[tid >> 6] = s; ssq[tid >> 6] = sq; }
    __syncthreads();
    s  = ss[0] + ss[1] + ss[2] + ss[3];
    sq = ssq[0] + ssq[1] + ssq[2] + ssq[3];
    float mu  = s * (1.f / DMODEL);
    float var = sq * (1.f / DMODEL) - mu * mu;
    float rs  = rsqrtf(var + 1e-5f);
    float2 wv = ((const float2*)w)[tid];
    float2 bv = ((const float2*)b)[tid];
    float2 o;
    o.x = (v.x - mu) * rs * wv.x + bv.x;
    o.y = (v.y - mu) * rs * wv.y + bv.y;
    ((float2*)(out + (size_t)row * DMODEL))[tid] = o;
}

// ---------------- depthwise causal conv(3) + silu ----------------
__global__ __launch_bounds__(256)
void conv_silu(const float* __restrict__ xz, const float* __restrict__ cw,
               const float* __restrict__ cb, float* __restrict__ u)
{
    int idx = blockIdx.x * 256 + threadIdx.x;   // < MROWS * DINNER
    int d   = idx & (DINNER - 1);
    int row = idx >> 10;
    int t   = row & (T_SEQ - 1);
    float acc = cb[d];
    #pragma unroll
    for (int k = 0; k < 3; ++k) {
        int tt = t - 2 + k;
        if (tt >= 0)
            acc += xz[(size_t)(row - 2 + k) * (2 * DINNER) + d] * cw[d * 3 + k];
    }
    u[(size_t)row * DINNER + d] = acc / (1.f + __expf(-acc));
}

// ---------------- chunked selective scan ----------------
// Layout for all phases: 16 states (lane s) x 16 channels per 256-thread block.
// Phase 1: per (chunk, channel, state): local scan from h=0 over CLEN steps.
//   Emits hend[c][ch][s] and P[c][ch][s] = exp(A * sum(delta)) = prod a_t.
__global__ __launch_bounds__(256)
void scan_phase1(const float* __restrict__ delta, const float* __restrict__ u,
                 const float* __restrict__ xdbl, const float* __restrict__ A_log,
                 float* __restrict__ hend, float* __restrict__ Pbuf)
{
    int tid  = threadIdx.x;
    int s    = tid & 15;
    int cloc = tid >> 4;
    int ch   = blockIdx.x * 16 + cloc;      // 0..8191
    int c    = blockIdx.y;                  // chunk
    int b    = ch >> 10;
    int d    = ch & (DINNER - 1);
    float Aval = -__expf(A_log[d * DSTATE + s]);
    float h = 0.f, sumd = 0.f;
    int row = b * T_SEQ + c * CLEN;
    const float* dp = delta + (size_t)row * DINNER + d;
    const float* up = u     + (size_t)row * DINNER + d;
    const float* xp = xdbl  + (size_t)row * 64 + DTRANK + s;
    for (int t = 0; t < CLEN; ++t) {
        float dlt = dp[(size_t)t * DINNER];
        float ut  = up[(size_t)t * DINNER];
        float Bv  = xp[(size_t)t * 64];
        float e = __expf(dlt * Aval);
        h = e * h + (dlt * ut) * Bv;
        sumd += dlt;
    }
    size_t o = ((size_t)c * NCHAN + ch) * DSTATE + s;
    hend[o] = h;
    Pbuf[o] = __expf(Aval * sumd);
}

// Phase 2: per (channel, state): 8-step sequential chunk combine -> hin[c].
__global__ __launch_bounds__(256)
void scan_phase2(const float* __restrict__ hend, const float* __restrict__ Pbuf,
                 float* __restrict__ hin)
{
    int idx = blockIdx.x * 256 + threadIdx.x;   // ch*16+s, coalesced in s
    float h = 0.f;
    #pragma unroll
    for (int c = 0; c < NCH; ++c) {
        size_t o = (size_t)c * (NCHAN * DSTATE) + idx;
        hin[o] = h;
        h = Pbuf[o] * h + hend[o];
    }
}

// Phase 3: rescan each chunk from hin; y = sum_s h*C; fused epilogue
//   yy = (y + D*u) * silu(z). yy aliases delta (same-wave read-before-write).
__global__ __launch_bounds__(256)
void scan_phase3(const float* __restrict__ delta, const float* __restrict__ u,
                 const float* __restrict__ xdbl, const float* __restrict__ A_log,
                 const float* __restrict__ Dp, const float* __restrict__ xz,
                 const float* __restrict__ hin, float* __restrict__ yy)
{
    int tid  = threadIdx.x;
    int s    = tid & 15;
    int cloc = tid >> 4;
    int ch   = blockIdx.x * 16 + cloc;
    int c    = blockIdx.y;
    int b    = ch >> 10;
    int d    = ch & (DINNER - 1);
    float Aval = -__expf(A_log[d * DSTATE + s]);
    float Dval = Dp[d];
    float h = hin[((size_t)c * NCHAN + ch) * DSTATE + s];
    int row0 = b * T_SEQ + c * CLEN;
    const float* dp = delta + (size_t)row0 * DINNER + d;
    const float* up = u     + (size_t)row0 * DINNER + d;
    const float* xp = xdbl  + (size_t)row0 * 64 + DTRANK + s;
    const float* zp = xz    + (size_t)row0 * (2 * DINNER) + DINNER + d;
    float*       yp = yy    + (size_t)row0 * DINNER + d;
    for (int t = 0; t < CLEN; ++t) {
        float dlt = dp[(size_t)t * DINNER];
        float ut  = up[(size_t)t * DINNER];
        float Bv  = xp[(size_t)t * 64];
        float Cv  = xp[(size_t)t * 64 + DSTATE];
        float e = __expf(dlt * Aval);
        h = e * h + (dlt * ut) * Bv;
        float p = h * Cv;
        p += __shfl_xor(p, 1);
        p += __shfl_xor(p, 2);
        p += __shfl_xor(p, 4);
        p += __shfl_xor(p, 8);
        if (s == 0) {
            float z = zp[(size_t)t * (2 * DINNER)];
            float sil = z / (1.f + __expf(-z));
            yp[(size_t)t * DINNER] = (p + Dval * ut) * sil;
        }
    }
}

// ---------------- masked mean pool ----------------
__global__ __launch_bounds__(512)
void pool_kernel(const float* __restrict__ h, const int* __restrict__ lengths,
                 float* __restrict__ pooled)
{
    int b  = blockIdx.x;
    int dm = threadIdx.x;   // 512
    int len = lengths[b];
    float cnt = fmaxf((float)len, 1.f);
    float acc = 0.f;
    for (int t = 0; t < len; ++t)
        acc += h[((size_t)b * T_SEQ + t) * DMODEL + dm];
    pooled[b * DMODEL + dm] = acc / cnt;
}

extern "C" void kernel_launch(void* const* d_in, const int* in_sizes, int n_in,
                              void* d_out, int out_size, void* d_ws, size_t ws_size,
                              hipStream_t stream)
{
    const float* x        = (const float*)d_in[0];
    const int*   lengths  = (const int*)d_in[1];
    const float* proj_w   = (const float*)d_in[2];
    const float* proj_b   = (const float*)d_in[3];
    const float* ln_w     = (const float*)d_in[4];
    const float* ln_b     = (const float*)d_in[5];
    const float* in_w     = (const float*)d_in[6];
    const float* conv_w   = (const float*)d_in[7];
    const float* conv_b   = (const float*)d_in[8];
    const float* xproj_w  = (const float*)d_in[9];
    const float* dtproj_w = (const float*)d_in[10];
    const float* dtproj_b = (const float*)d_in[11];
    const float* A_log    = (const float*)d_in[12];
    const float* Dp       = (const float*)d_in[13];
    const float* out_w    = (const float*)d_in[14];

    float* h      = (float*)d_out;                 // seq_out lives here (8192x512)
    float* pooled = h + (size_t)MROWS * DMODEL;

    float* ws    = (float*)d_ws;
    float* h_ln  = ws;                                    // 8192*512
    float* xz    = h_ln  + (size_t)MROWS * DMODEL;        // 8192*2048
    float* u     = xz    + (size_t)MROWS * 2 * DINNER;    // 8192*1024
    float* xdbl  = u     + (size_t)MROWS * DINNER;        // 8192*64
    float* delta = xdbl  + (size_t)MROWS * 64;            // 8192*1024 (also yy)
    float* hend  = delta + (size_t)MROWS * DINNER;        // 8*8192*16
    float* Pbuf  = hend  + (size_t)NCH * NCHAN * DSTATE;  // 8*8192*16
    float* hinb  = Pbuf  + (size_t)NCH * NCHAN * DSTATE;  // 8*8192*16

    // h = x @ proj_w + proj_b   (M=8192, K=80, N=512)
    gemm_f32<1><<<dim3(DMODEL / BN, MROWS / BM), 256, 0, stream>>>(
        x, 80, proj_w, proj_b, h, DMODEL, MROWS, DMODEL, 80);

    for (int l = 0; l < NLAYER; ++l) {
        ln_kernel<<<MROWS, 256, 0, stream>>>(h, ln_w + l * DMODEL, ln_b + l * DMODEL, h_ln);

        // xz = h_ln @ in_w   (K=512, N=2048)
        gemm_f32<0><<<dim3(2 * DINNER / BN, MROWS / BM), 256, 0, stream>>>(
            h_ln, DMODEL, in_w + (size_t)l * DMODEL * 2 * DINNER, nullptr,
            xz, 2 * DINNER, MROWS, 2 * DINNER, DMODEL);

        conv_silu<<<(MROWS * DINNER) / 256, 256, 0, stream>>>(
            xz, conv_w + l * DINNER * 3, conv_b + l * DINNER, u);

        // x_dbl = u @ xproj_w   (K=1024, N=64)
        gemm_f32<0><<<dim3(64 / BN, MROWS / BM), 256, 0, stream>>>(
            u, DINNER, xproj_w + (size_t)l * DINNER * 64, nullptr,
            xdbl, 64, MROWS, 64, DINNER);

        // delta = softplus(dt @ dtproj_w + dtproj_b)   (K=32, N=1024)
        gemm_f32<2><<<dim3(DINNER / BN, MROWS / BM), 256, 0, stream>>>(
            xdbl, 64, dtproj_w + (size_t)l * DTRANK * DINNER, dtproj_b + l * DINNER,
            delta, DINNER, MROWS, DINNER, DTRANK);

        // chunked selective scan
        scan_phase1<<<dim3(NCHAN / 16, NCH), 256, 0, stream>>>(
            delta, u, xdbl, A_log + (size_t)l * DINNER * DSTATE, hend, Pbuf);
        scan_phase2<<<(NCHAN * DSTATE) / 256, 256, 0, stream>>>(hend, Pbuf, hinb);
        scan_phase3<<<dim3(NCHAN / 16, NCH), 256, 0, stream>>>(
            delta, u, xdbl, A_log + (size_t)l * DINNER * DSTATE, Dp + l * DINNER,
            xz, hinb, delta);

        // h += yy @ out_w   (K=1024, N=512)
        gemm_f32<3><<<dim3(DMODEL / BN, MROWS / BM), 256, 0, stream>>>(
            delta, DINNER, out_w + (size_t)l * DINNER * DMODEL, nullptr,
            h, DMODEL, MROWS, DMODEL, DINNER);
    }

    pool_kernel<<<BATCH, DMODEL, 0, stream>>>(h, lengths, pooled);
}

// Round 3
// 2040.798 us; speedup vs baseline: 2.5432x; 1.5558x over previous
//
#include <hip/hip_runtime.h>
#include <math.h>

#define T_SEQ   1024
#define BATCH   8
#define DMODEL  512
#define DINNER  1024
#define DSTATE  16
#define DTRANK  32
#define NLAYER  4
#define MROWS   (BATCH * T_SEQ)   // 8192
#define NCH     8                 // scan chunks
#define CLEN    (T_SEQ / NCH)     // 128
#define NCHAN   (BATCH * DINNER)  // 8192 channels

typedef float f32x4 __attribute__((ext_vector_type(4)));
typedef short s16x8 __attribute__((ext_vector_type(8)));

__device__ __forceinline__ unsigned short f2bf(float f) {
    unsigned u = __builtin_bit_cast(unsigned, f);
    u = (u + 0x7FFFu + ((u >> 16) & 1u)) >> 16;
    return (unsigned short)u;
}

// ---------------- bf16 MFMA GEMM ----------------
// C[M,N] fp32 = A[M,K] bf16 @ B^T[N,K] bf16.  EPI 0: store; 3: C += acc.
// 128x128 tile, BK=32, 4 waves each 64x64. LDS XOR-swizzled (T2) both sides.
template<int EPI>
__global__ __launch_bounds__(256)
void gemm_mfma(const unsigned short* __restrict__ A,
               const unsigned short* __restrict__ BT,
               float* __restrict__ C, int M, int N, int K)
{
    __shared__ __align__(16) unsigned short As[128 * 32];
    __shared__ __align__(16) unsigned short Bs[128 * 32];
    const int tid  = threadIdx.x;
    const int bn   = blockIdx.x * 128;
    const int bm   = blockIdx.y * 128;
    const int wave = tid >> 6;
    const int lane = tid & 63;
    const int wm = (wave >> 1) * 64;
    const int wn = (wave & 1) * 64;

    // swizzled 16B-unit index for (tile_row, k-octet)
    #define UNIT(row, kg) ((((row) << 2) | (kg)) ^ ((row) & 7))

    const int srow = tid >> 2;       // 0..63
    const int skg  = tid & 3;        // 0..3
    const int u0 = UNIT(srow, skg);
    const int u1 = UNIT(srow + 64, skg);

    const int r15 = lane & 15;
    const int kgl = lane >> 4;
    int aoff[4], boff[4];
    #pragma unroll
    for (int i = 0; i < 4; ++i) {
        aoff[i] = UNIT(wm + i * 16 + r15, kgl) * 8;
        boff[i] = UNIT(wn + i * 16 + r15, kgl) * 8;
    }

    const unsigned short* Ap0 = A  + (size_t)(bm + srow)      * K + skg * 8;
    const unsigned short* Ap1 = A  + (size_t)(bm + srow + 64) * K + skg * 8;
    const unsigned short* Bp0 = BT + (size_t)(bn + srow)      * K + skg * 8;
    const unsigned short* Bp1 = BT + (size_t)(bn + srow + 64) * K + skg * 8;

    f32x4 zero = {0.f, 0.f, 0.f, 0.f};
    f32x4 acc[4][4];
    #pragma unroll
    for (int i = 0; i < 4; ++i)
        #pragma unroll
        for (int j = 0; j < 4; ++j) acc[i][j] = zero;

    for (int k0 = 0; k0 < K; k0 += 32) {
        uint4 a0 = *(const uint4*)(Ap0 + k0);
        uint4 a1 = *(const uint4*)(Ap1 + k0);
        uint4 b0 = *(const uint4*)(Bp0 + k0);
        uint4 b1 = *(const uint4*)(Bp1 + k0);
        __syncthreads();
        *(uint4*)(As + u0 * 8) = a0;
        *(uint4*)(As + u1 * 8) = a1;
        *(uint4*)(Bs + u0 * 8) = b0;
        *(uint4*)(Bs + u1 * 8) = b1;
        __syncthreads();
        s16x8 fa[4], fb[4];
        #pragma unroll
        for (int i = 0; i < 4; ++i) {
            fa[i] = *(const s16x8*)(As + aoff[i]);
            fb[i] = *(const s16x8*)(Bs + boff[i]);
        }
        #pragma unroll
        for (int mi = 0; mi < 4; ++mi)
            #pragma unroll
            for (int ni = 0; ni < 4; ++ni)
                acc[mi][ni] = __builtin_amdgcn_mfma_f32_16x16x32_bf16(
                    fa[mi], fb[ni], acc[mi][ni], 0, 0, 0);
    }

    // C/D layout: col = lane&15, row = (lane>>4)*4 + reg  [m89 verified]
    #pragma unroll
    for (int mi = 0; mi < 4; ++mi) {
        #pragma unroll
        for (int j = 0; j < 4; ++j) {
            int row = bm + wm + mi * 16 + kgl * 4 + j;
            float* cp = &C[(size_t)row * N + bn + wn + r15];
            #pragma unroll
            for (int ni = 0; ni < 4; ++ni) {
                float v = acc[mi][ni][j];
                if (EPI == 3) v += cp[ni * 16];
                cp[ni * 16] = v;
            }
        }
    }
    #undef UNIT
}

// ---------------- weight transpose + fp32->bf16 ----------------
// src: [L][R][Cc] fp32  ->  dst: [L][Cc][R] bf16
__global__ __launch_bounds__(256)
void wconvT(const float* __restrict__ W, unsigned short* __restrict__ WT,
            int R, int Cc)
{
    int l = blockIdx.z;
    const float* src = W + (size_t)l * R * Cc;
    unsigned short* dst = WT + (size_t)l * R * Cc;
    __shared__ float tile[32][33];
    int c0 = blockIdx.x * 32, r0 = blockIdx.y * 32;
    int tx = threadIdx.x & 31, ty = threadIdx.x >> 5;  // 32 x 8
    #pragma unroll
    for (int i = 0; i < 4; ++i)
        tile[ty + i * 8][tx] = src[(size_t)(r0 + ty + i * 8) * Cc + c0 + tx];
    __syncthreads();
    #pragma unroll
    for (int i = 0; i < 4; ++i)
        dst[(size_t)(c0 + ty + i * 8) * R + r0 + tx] = f2bf(tile[tx][ty + i * 8]);
}

// ---------------- generic tiled fp32 GEMM (small ops) ----------------
#define BM 64
#define BN 64
#define BK 16

template<int EPI>
__global__ __launch_bounds__(256)
void gemm_f32(const float* __restrict__ A, int lda,
              const float* __restrict__ B,
              const float* __restrict__ bias,
              float* __restrict__ C, int ldc,
              int M, int N, int K)
{
    __shared__ float As[BK][BM];
    __shared__ float Bs[BK][BN];
    const int bn = blockIdx.x * BN;
    const int bm = blockIdx.y * BM;
    const int tid = threadIdx.x;
    const int tx = tid & 15;
    const int ty = tid >> 4;
    const int ar = tid >> 2;
    const int ac = (tid & 3) * 4;
    const int br = tid >> 4;
    const int bc = (tid & 15) * 4;

    float acc[4][4] = {};

    for (int k0 = 0; k0 < K; k0 += BK) {
        float4 av = *(const float4*)&A[(bm + ar) * lda + k0 + ac];
        float4 bv = *(const float4*)&B[(k0 + br) * N + bn + bc];
        As[ac + 0][ar] = av.x;
        As[ac + 1][ar] = av.y;
        As[ac + 2][ar] = av.z;
        As[ac + 3][ar] = av.w;
        *(float4*)&Bs[br][bc] = bv;
        __syncthreads();
        #pragma unroll
        for (int kk = 0; kk < BK; ++kk) {
            float4 a = *(const float4*)&As[kk][ty * 4];
            float4 b = *(const float4*)&Bs[kk][tx * 4];
            float af[4] = {a.x, a.y, a.z, a.w};
            float bfv[4] = {b.x, b.y, b.z, b.w};
            #pragma unroll
            for (int i = 0; i < 4; ++i)
                #pragma unroll
                for (int j = 0; j < 4; ++j)
                    acc[i][j] = fmaf(af[i], bfv[j], acc[i][j]);
        }
        __syncthreads();
    }

    #pragma unroll
    for (int i = 0; i < 4; ++i) {
        int r = bm + ty * 4 + i;
        float* cp = &C[r * ldc + bn + tx * 4];
        float v[4];
        #pragma unroll
        for (int j = 0; j < 4; ++j) {
            float xv = acc[i][j];
            if (EPI == 1) xv += bias[bn + tx * 4 + j];
            if (EPI == 2) {
                xv += bias[bn + tx * 4 + j];
                xv = (xv > 20.f) ? xv : log1pf(__expf(xv));
            }
            v[j] = xv;
        }
        if (EPI == 3) {
            float4 old = *(const float4*)cp;
            v[0] += old.x; v[1] += old.y; v[2] += old.z; v[3] += old.w;
        }
        float4 o; o.x = v[0]; o.y = v[1]; o.z = v[2]; o.w = v[3];
        *(float4*)cp = o;
    }
}

// ---------------- LayerNorm -> bf16 ----------------
__global__ __launch_bounds__(256)
void ln_kernel(const float* __restrict__ x, const float* __restrict__ w,
               const float* __restrict__ b, unsigned short* __restrict__ out)
{
    int row = blockIdx.x;
    const float* xr = x + (size_t)row * DMODEL;
    int tid = threadIdx.x;
    float2 v = ((const float2*)xr)[tid];
    float s  = v.x + v.y;
    float sq = v.x * v.x + v.y * v.y;
    #pragma unroll
    for (int off = 32; off > 0; off >>= 1) {
        s  += __shfl_down(s, off);
        sq += __shfl_down(sq, off);
    }
    __shared__ float ss[4], ssq[4];
    if ((tid & 63) == 0) { ss[tid >> 6] = s; ssq[tid >> 6] = sq; }
    __syncthreads();
    s  = ss[0] + ss[1] + ss[2] + ss[3];
    sq = ssq[0] + ssq[1] + ssq[2] + ssq[3];
    float mu  = s * (1.f / DMODEL);
    float var = sq * (1.f / DMODEL) - mu * mu;
    float rs  = rsqrtf(var + 1e-5f);
    float2 wv = ((const float2*)w)[tid];
    float2 bv = ((const float2*)b)[tid];
    float o0 = (v.x - mu) * rs * wv.x + bv.x;
    float o1 = (v.y - mu) * rs * wv.y + bv.y;
    unsigned pack = (unsigned)f2bf(o0) | ((unsigned)f2bf(o1) << 16);
    ((unsigned*)(out + (size_t)row * DMODEL))[tid] = pack;
}

// ---------------- depthwise causal conv(3) + silu ----------------
__global__ __launch_bounds__(256)
void conv_silu(const float* __restrict__ xz, const float* __restrict__ cw,
               const float* __restrict__ cb, float* __restrict__ u)
{
    int idx = blockIdx.x * 256 + threadIdx.x;
    int d   = idx & (DINNER - 1);
    int row = idx >> 10;
    int t   = row & (T_SEQ - 1);
    float acc = cb[d];
    #pragma unroll
    for (int k = 0; k < 3; ++k) {
        int tt = t - 2 + k;
        if (tt >= 0)
            acc += xz[(size_t)(row - 2 + k) * (2 * DINNER) + d] * cw[d * 3 + k];
    }
    u[(size_t)row * DINNER + d] = acc / (1.f + __expf(-acc));
}

// ---------------- chunked selective scan ----------------
__global__ __launch_bounds__(256)
void scan_phase1(const float* __restrict__ delta, const float* __restrict__ u,
                 const float* __restrict__ xdbl, const float* __restrict__ A_log,
                 float* __restrict__ hend, float* __restrict__ Pbuf)
{
    int tid  = threadIdx.x;
    int s    = tid & 15;
    int cloc = tid >> 4;
    int ch   = blockIdx.x * 16 + cloc;
    int c    = blockIdx.y;
    int b    = ch >> 10;
    int d    = ch & (DINNER - 1);
    float Aval = -__expf(A_log[d * DSTATE + s]);
    float h = 0.f, sumd = 0.f;
    int row = b * T_SEQ + c * CLEN;
    const float* dp = delta + (size_t)row * DINNER + d;
    const float* up = u     + (size_t)row * DINNER + d;
    const float* xp = xdbl  + (size_t)row * 64 + DTRANK + s;
    for (int t = 0; t < CLEN; ++t) {
        float dlt = dp[(size_t)t * DINNER];
        float ut  = up[(size_t)t * DINNER];
        float Bv  = xp[(size_t)t * 64];
        float e = __expf(dlt * Aval);
        h = e * h + (dlt * ut) * Bv;
        sumd += dlt;
    }
    size_t o = ((size_t)c * NCHAN + ch) * DSTATE + s;
    hend[o] = h;
    Pbuf[o] = __expf(Aval * sumd);
}

__global__ __launch_bounds__(256)
void scan_phase2(const float* __restrict__ hend, const float* __restrict__ Pbuf,
                 float* __restrict__ hin)
{
    int idx = blockIdx.x * 256 + threadIdx.x;
    float h = 0.f;
    #pragma unroll
    for (int c = 0; c < NCH; ++c) {
        size_t o = (size_t)c * (NCHAN * DSTATE) + idx;
        hin[o] = h;
        h = Pbuf[o] * h + hend[o];
    }
}

// Phase 3: rescan; fused epilogue (y + D*u)*silu(z) -> yy (bf16, feeds out_w GEMM)
__global__ __launch_bounds__(256)
void scan_phase3(const float* __restrict__ delta, const float* __restrict__ u,
                 const float* __restrict__ xdbl, const float* __restrict__ A_log,
                 const float* __restrict__ Dp, const float* __restrict__ xz,
                 const float* __restrict__ hin, unsigned short* __restrict__ yy)
{
    int tid  = threadIdx.x;
    int s    = tid & 15;
    int cloc = tid >> 4;
    int ch   = blockIdx.x * 16 + cloc;
    int c    = blockIdx.y;
    int b    = ch >> 10;
    int d    = ch & (DINNER - 1);
    float Aval = -__expf(A_log[d * DSTATE + s]);
    float Dval = Dp[d];
    float h = hin[((size_t)c * NCHAN + ch) * DSTATE + s];
    int row0 = b * T_SEQ + c * CLEN;
    const float* dp = delta + (size_t)row0 * DINNER + d;
    const float* up = u     + (size_t)row0 * DINNER + d;
    const float* xp = xdbl  + (size_t)row0 * 64 + DTRANK + s;
    const float* zp = xz    + (size_t)row0 * (2 * DINNER) + DINNER + d;
    unsigned short* yp = yy + (size_t)row0 * DINNER + d;
    for (int t = 0; t < CLEN; ++t) {
        float dlt = dp[(size_t)t * DINNER];
        float ut  = up[(size_t)t * DINNER];
        float Bv  = xp[(size_t)t * 64];
        float Cv  = xp[(size_t)t * 64 + DSTATE];
        float e = __expf(dlt * Aval);
        h = e * h + (dlt * ut) * Bv;
        float p = h * Cv;
        p += __shfl_xor(p, 1);
        p += __shfl_xor(p, 2);
        p += __shfl_xor(p, 4);
        p += __shfl_xor(p, 8);
        if (s == 0) {
            float z = zp[(size_t)t * (2 * DINNER)];
            float sil = z / (1.f + __expf(-z));
            yp[(size_t)t * DINNER] = f2bf((p + Dval * ut) * sil);
        }
    }
}

// ---------------- masked mean pool ----------------
__global__ __launch_bounds__(512)
void pool_kernel(const float* __restrict__ h, const int* __restrict__ lengths,
                 float* __restrict__ pooled)
{
    int b  = blockIdx.x;
    int dm = threadIdx.x;
    int len = lengths[b];
    float cnt = fmaxf((float)len, 1.f);
    float acc = 0.f;
    for (int t = 0; t < len; ++t)
        acc += h[((size_t)b * T_SEQ + t) * DMODEL + dm];
    pooled[b * DMODEL + dm] = acc / cnt;
}

extern "C" void kernel_launch(void* const* d_in, const int* in_sizes, int n_in,
                              void* d_out, int out_size, void* d_ws, size_t ws_size,
                              hipStream_t stream)
{
    const float* x        = (const float*)d_in[0];
    const int*   lengths  = (const int*)d_in[1];
    const float* proj_w   = (const float*)d_in[2];
    const float* proj_b   = (const float*)d_in[3];
    const float* ln_w     = (const float*)d_in[4];
    const float* ln_b     = (const float*)d_in[5];
    const float* in_w     = (const float*)d_in[6];
    const float* conv_w   = (const float*)d_in[7];
    const float* conv_b   = (const float*)d_in[8];
    const float* xproj_w  = (const float*)d_in[9];
    const float* dtproj_w = (const float*)d_in[10];
    const float* dtproj_b = (const float*)d_in[11];
    const float* A_log    = (const float*)d_in[12];
    const float* Dp       = (const float*)d_in[13];
    const float* out_w    = (const float*)d_in[14];

    float* h      = (float*)d_out;                 // seq_out (8192x512)
    float* pooled = h + (size_t)MROWS * DMODEL;

    float* ws    = (float*)d_ws;
    float* xz    = ws;                                    // 16M f
    float* u     = xz    + (size_t)MROWS * 2 * DINNER;    // 8M f
    float* xdbl  = u     + (size_t)MROWS * DINNER;        // 0.5M f
    float* delta = xdbl  + (size_t)MROWS * 64;            // 8M f
    float* hend  = delta + (size_t)MROWS * DINNER;        // 128K f
    float* Pbuf  = hend  + (size_t)NCH * NCHAN * DSTATE;  // 128K f
    float* hinb  = Pbuf  + (size_t)NCH * NCHAN * DSTATE;  // 128K f
    unsigned short* hlnb  = (unsigned short*)(hinb + (size_t)NCH * NCHAN * DSTATE); // 4M bf16
    unsigned short* yyb   = hlnb + (size_t)MROWS * DMODEL;                          // 8M bf16
    unsigned short* inwT  = yyb  + (size_t)MROWS * DINNER;                          // 4M bf16
    unsigned short* outwT = inwT + (size_t)NLAYER * DMODEL * 2 * DINNER;            // 2M bf16

    // Weight prep (once per call): in_w [512][2048] -> [2048][512] bf16; out_w [1024][512] -> [512][1024] bf16
    wconvT<<<dim3(2 * DINNER / 32, DMODEL / 32, NLAYER), 256, 0, stream>>>(in_w, inwT, DMODEL, 2 * DINNER);
    wconvT<<<dim3(DMODEL / 32, DINNER / 32, NLAYER), 256, 0, stream>>>(out_w, outwT, DINNER, DMODEL);

    // h = x @ proj_w + proj_b   (fp32; K=80)
    gemm_f32<1><<<dim3(DMODEL / BN, MROWS / BM), 256, 0, stream>>>(
        x, 80, proj_w, proj_b, h, DMODEL, MROWS, DMODEL, 80);

    for (int l = 0; l < NLAYER; ++l) {
        ln_kernel<<<MROWS, 256, 0, stream>>>(h, ln_w + l * DMODEL, ln_b + l * DMODEL, hlnb);

        // xz = h_ln @ in_w   (bf16 MFMA: M=8192, N=2048, K=512)
        gemm_mfma<0><<<dim3(2 * DINNER / 128, MROWS / 128), 256, 0, stream>>>(
            hlnb, inwT + (size_t)l * DMODEL * 2 * DINNER, xz, MROWS, 2 * DINNER, DMODEL);

        conv_silu<<<(MROWS * DINNER) / 256, 256, 0, stream>>>(
            xz, conv_w + l * DINNER * 3, conv_b + l * DINNER, u);

        // x_dbl = u @ xproj_w   (fp32: K=1024, N=64)
        gemm_f32<0><<<dim3(64 / BN, MROWS / BM), 256, 0, stream>>>(
            u, DINNER, xproj_w + (size_t)l * DINNER * 64, nullptr,
            xdbl, 64, MROWS, 64, DINNER);

        // delta = softplus(dt @ dtproj_w + dtproj_b)   (fp32: K=32, N=1024)
        gemm_f32<2><<<dim3(DINNER / BN, MROWS / BM), 256, 0, stream>>>(
            xdbl, 64, dtproj_w + (size_t)l * DTRANK * DINNER, dtproj_b + l * DINNER,
            delta, DINNER, MROWS, DINNER, DTRANK);

        // chunked selective scan
        scan_phase1<<<dim3(NCHAN / 16, NCH), 256, 0, stream>>>(
            delta, u, xdbl, A_log + (size_t)l * DINNER * DSTATE, hend, Pbuf);
        scan_phase2<<<(NCHAN * DSTATE) / 256, 256, 0, stream>>>(hend, Pbuf, hinb);
        scan_phase3<<<dim3(NCHAN / 16, NCH), 256, 0, stream>>>(
            delta, u, xdbl, A_log + (size_t)l * DINNER * DSTATE, Dp + l * DINNER,
            xz, hinb, yyb);

        // h += yy @ out_w   (bf16 MFMA: M=8192, N=512, K=1024, residual)
        gemm_mfma<3><<<dim3(DMODEL / 128, MROWS / 128), 256, 0, stream>>>(
            yyb, outwT + (size_t)l * DINNER * DMODEL, h, MROWS, DMODEL, DINNER);
    }

    pool_kernel<<<BATCH, DMODEL, 0, stream>>>(h, lengths, pooled);
}

// Round 4
// 1278.334 us; speedup vs baseline: 4.0601x; 1.5965x over previous
//
#include <hip/hip_runtime.h>
#include <math.h>

#define T_SEQ   1024
#define BATCH   8
#define DMODEL  512
#define DINNER  1024
#define DSTATE  16
#define DTRANK  32
#define NLAYER  4
#define MROWS   (BATCH * T_SEQ)   // 8192
#define NCH     32                // scan chunks
#define CLEN    (T_SEQ / NCH)     // 32
#define NCHAN   (BATCH * DINNER)  // 8192 channels

typedef float f32x4 __attribute__((ext_vector_type(4)));
typedef short s16x8 __attribute__((ext_vector_type(8)));

__device__ __forceinline__ unsigned short f2bf(float f) {
    unsigned u = __builtin_bit_cast(unsigned, f);
    u = (u + 0x7FFFu + ((u >> 16) & 1u)) >> 16;
    return (unsigned short)u;
}

// ---------------- bf16 MFMA GEMM ----------------
// C[M,N] fp32 = A[M,K] bf16 @ B^T[N,K] bf16.  EPI 0: store; 3: C += acc.
template<int EPI>
__global__ __launch_bounds__(256)
void gemm_mfma(const unsigned short* __restrict__ A,
               const unsigned short* __restrict__ BT,
               float* __restrict__ C, int M, int N, int K)
{
    __shared__ __align__(16) unsigned short As[128 * 32];
    __shared__ __align__(16) unsigned short Bs[128 * 32];
    const int tid  = threadIdx.x;
    const int bn   = blockIdx.x * 128;
    const int bm   = blockIdx.y * 128;
    const int wave = tid >> 6;
    const int lane = tid & 63;
    const int wm = (wave >> 1) * 64;
    const int wn = (wave & 1) * 64;

    #define UNIT(row, kg) ((((row) << 2) | (kg)) ^ ((row) & 7))

    const int srow = tid >> 2;
    const int skg  = tid & 3;
    const int u0 = UNIT(srow, skg);
    const int u1 = UNIT(srow + 64, skg);

    const int r15 = lane & 15;
    const int kgl = lane >> 4;
    int aoff[4], boff[4];
    #pragma unroll
    for (int i = 0; i < 4; ++i) {
        aoff[i] = UNIT(wm + i * 16 + r15, kgl) * 8;
        boff[i] = UNIT(wn + i * 16 + r15, kgl) * 8;
    }

    const unsigned short* Ap0 = A  + (size_t)(bm + srow)      * K + skg * 8;
    const unsigned short* Ap1 = A  + (size_t)(bm + srow + 64) * K + skg * 8;
    const unsigned short* Bp0 = BT + (size_t)(bn + srow)      * K + skg * 8;
    const unsigned short* Bp1 = BT + (size_t)(bn + srow + 64) * K + skg * 8;

    f32x4 zero = {0.f, 0.f, 0.f, 0.f};
    f32x4 acc[4][4];
    #pragma unroll
    for (int i = 0; i < 4; ++i)
        #pragma unroll
        for (int j = 0; j < 4; ++j) acc[i][j] = zero;

    for (int k0 = 0; k0 < K; k0 += 32) {
        uint4 a0 = *(const uint4*)(Ap0 + k0);
        uint4 a1 = *(const uint4*)(Ap1 + k0);
        uint4 b0 = *(const uint4*)(Bp0 + k0);
        uint4 b1 = *(const uint4*)(Bp1 + k0);
        __syncthreads();
        *(uint4*)(As + u0 * 8) = a0;
        *(uint4*)(As + u1 * 8) = a1;
        *(uint4*)(Bs + u0 * 8) = b0;
        *(uint4*)(Bs + u1 * 8) = b1;
        __syncthreads();
        s16x8 fa[4], fb[4];
        #pragma unroll
        for (int i = 0; i < 4; ++i) {
            fa[i] = *(const s16x8*)(As + aoff[i]);
            fb[i] = *(const s16x8*)(Bs + boff[i]);
        }
        #pragma unroll
        for (int mi = 0; mi < 4; ++mi)
            #pragma unroll
            for (int ni = 0; ni < 4; ++ni)
                acc[mi][ni] = __builtin_amdgcn_mfma_f32_16x16x32_bf16(
                    fa[mi], fb[ni], acc[mi][ni], 0, 0, 0);
    }

    #pragma unroll
    for (int mi = 0; mi < 4; ++mi) {
        #pragma unroll
        for (int j = 0; j < 4; ++j) {
            int row = bm + wm + mi * 16 + kgl * 4 + j;
            float* cp = &C[(size_t)row * N + bn + wn + r15];
            #pragma unroll
            for (int ni = 0; ni < 4; ++ni) {
                float v = acc[mi][ni][j];
                if (EPI == 3) v += cp[ni * 16];
                cp[ni * 16] = v;
            }
        }
    }
    #undef UNIT
}

// ---------------- weight transpose + fp32->bf16 ----------------
__global__ __launch_bounds__(256)
void wconvT(const float* __restrict__ W, unsigned short* __restrict__ WT,
            int R, int Cc)
{
    int l = blockIdx.z;
    const float* src = W + (size_t)l * R * Cc;
    unsigned short* dst = WT + (size_t)l * R * Cc;
    __shared__ float tile[32][33];
    int c0 = blockIdx.x * 32, r0 = blockIdx.y * 32;
    int tx = threadIdx.x & 31, ty = threadIdx.x >> 5;
    #pragma unroll
    for (int i = 0; i < 4; ++i)
        tile[ty + i * 8][tx] = src[(size_t)(r0 + ty + i * 8) * Cc + c0 + tx];
    __syncthreads();
    #pragma unroll
    for (int i = 0; i < 4; ++i)
        dst[(size_t)(c0 + ty + i * 8) * R + r0 + tx] = f2bf(tile[tx][ty + i * 8]);
}

// ---------------- generic tiled fp32 GEMM (small ops) ----------------
#define BM 64
#define BN 64
#define BK 16

template<int EPI>
__global__ __launch_bounds__(256)
void gemm_f32(const float* __restrict__ A, int lda,
              const float* __restrict__ B,
              const float* __restrict__ bias,
              float* __restrict__ C, int ldc,
              int M, int N, int K)
{
    __shared__ float As[BK][BM];
    __shared__ float Bs[BK][BN];
    const int bn = blockIdx.x * BN;
    const int bm = blockIdx.y * BM;
    const int tid = threadIdx.x;
    const int tx = tid & 15;
    const int ty = tid >> 4;
    const int ar = tid >> 2;
    const int ac = (tid & 3) * 4;
    const int br = tid >> 4;
    const int bc = (tid & 15) * 4;

    float acc[4][4] = {};

    for (int k0 = 0; k0 < K; k0 += BK) {
        float4 av = *(const float4*)&A[(bm + ar) * lda + k0 + ac];
        float4 bv = *(const float4*)&B[(k0 + br) * N + bn + bc];
        As[ac + 0][ar] = av.x;
        As[ac + 1][ar] = av.y;
        As[ac + 2][ar] = av.z;
        As[ac + 3][ar] = av.w;
        *(float4*)&Bs[br][bc] = bv;
        __syncthreads();
        #pragma unroll
        for (int kk = 0; kk < BK; ++kk) {
            float4 a = *(const float4*)&As[kk][ty * 4];
            float4 b = *(const float4*)&Bs[kk][tx * 4];
            float af[4] = {a.x, a.y, a.z, a.w};
            float bfv[4] = {b.x, b.y, b.z, b.w};
            #pragma unroll
            for (int i = 0; i < 4; ++i)
                #pragma unroll
                for (int j = 0; j < 4; ++j)
                    acc[i][j] = fmaf(af[i], bfv[j], acc[i][j]);
        }
        __syncthreads();
    }

    #pragma unroll
    for (int i = 0; i < 4; ++i) {
        int r = bm + ty * 4 + i;
        float* cp = &C[r * ldc + bn + tx * 4];
        float v[4];
        #pragma unroll
        for (int j = 0; j < 4; ++j) {
            float xv = acc[i][j];
            if (EPI == 1) xv += bias[bn + tx * 4 + j];
            if (EPI == 2) {
                xv += bias[bn + tx * 4 + j];
                xv = (xv > 20.f) ? xv : log1pf(__expf(xv));
            }
            v[j] = xv;
        }
        if (EPI == 3) {
            float4 old = *(const float4*)cp;
            v[0] += old.x; v[1] += old.y; v[2] += old.z; v[3] += old.w;
        }
        float4 o; o.x = v[0]; o.y = v[1]; o.z = v[2]; o.w = v[3];
        *(float4*)cp = o;
    }
}

// ---------------- LayerNorm -> bf16 ----------------
__global__ __launch_bounds__(256)
void ln_kernel(const float* __restrict__ x, const float* __restrict__ w,
               const float* __restrict__ b, unsigned short* __restrict__ out)
{
    int row = blockIdx.x;
    const float* xr = x + (size_t)row * DMODEL;
    int tid = threadIdx.x;
    float2 v = ((const float2*)xr)[tid];
    float s  = v.x + v.y;
    float sq = v.x * v.x + v.y * v.y;
    #pragma unroll
    for (int off = 32; off > 0; off >>= 1) {
        s  += __shfl_down(s, off);
        sq += __shfl_down(sq, off);
    }
    __shared__ float ss[4], ssq[4];
    if ((tid & 63) == 0) { ss[tid >> 6] = s; ssq[tid >> 6] = sq; }
    __syncthreads();
    s  = ss[0] + ss[1] + ss[2] + ss[3];
    sq = ssq[0] + ssq[1] + ssq[2] + ssq[3];
    float mu  = s * (1.f / DMODEL);
    float var = sq * (1.f / DMODEL) - mu * mu;
    float rs  = rsqrtf(var + 1e-5f);
    float2 wv = ((const float2*)w)[tid];
    float2 bv = ((const float2*)b)[tid];
    float o0 = (v.x - mu) * rs * wv.x + bv.x;
    float o1 = (v.y - mu) * rs * wv.y + bv.y;
    unsigned pack = (unsigned)f2bf(o0) | ((unsigned)f2bf(o1) << 16);
    ((unsigned*)(out + (size_t)row * DMODEL))[tid] = pack;
}

// ---------------- depthwise causal conv(3) + silu ----------------
__global__ __launch_bounds__(256)
void conv_silu(const float* __restrict__ xz, const float* __restrict__ cw,
               const float* __restrict__ cb, float* __restrict__ u)
{
    int idx = blockIdx.x * 256 + threadIdx.x;
    int d   = idx & (DINNER - 1);
    int row = idx >> 10;
    int t   = row & (T_SEQ - 1);
    float acc = cb[d];
    #pragma unroll
    for (int k = 0; k < 3; ++k) {
        int tt = t - 2 + k;
        if (tt >= 0)
            acc += xz[(size_t)(row - 2 + k) * (2 * DINNER) + d] * cw[d * 3 + k];
    }
    u[(size_t)row * DINNER + d] = acc / (1.f + __expf(-acc));
}

// ---------------- chunked selective scan (channel-per-thread) ----------------
// Phase 1: thread = one channel, 16 states in regs. Local scan over CLEN from 0.
// Writes hend[c][ch][16] and sumd sd[c][ch].
__global__ __launch_bounds__(256)
void scan_phase1(const float* __restrict__ delta, const float* __restrict__ u,
                 const float* __restrict__ xdbl, const float* __restrict__ A_log,
                 float* __restrict__ hend, float* __restrict__ sd)
{
    __shared__ float Bsh[CLEN][DSTATE];
    int tid = threadIdx.x;
    int ch  = blockIdx.x * 256 + tid;
    int c   = blockIdx.y;
    int b   = ch >> 10;
    int d   = ch & (DINNER - 1);
    int row0 = b * T_SEQ + c * CLEN;
    if (tid < CLEN * DSTATE / 4) {   // 128 threads stage 32x16 floats
        int r = tid >> 2, col = (tid & 3) * 4;
        *(float4*)&Bsh[r][col] = *(const float4*)&xdbl[(size_t)(row0 + r) * 64 + DTRANK + col];
    }
    float A[DSTATE];
    const float* ap = A_log + (size_t)d * DSTATE;
    #pragma unroll
    for (int s = 0; s < DSTATE; ++s) A[s] = -__expf(ap[s]);
    __syncthreads();

    float h[DSTATE];
    #pragma unroll
    for (int s = 0; s < DSTATE; ++s) h[s] = 0.f;
    float sumd = 0.f;
    const float* dp = delta + (size_t)row0 * DINNER + d;
    const float* up = u     + (size_t)row0 * DINNER + d;
    for (int t = 0; t < CLEN; ++t) {
        float dlt = dp[(size_t)t * DINNER];
        float ut  = up[(size_t)t * DINNER];
        float du  = dlt * ut;
        sumd += dlt;
        #pragma unroll
        for (int s = 0; s < DSTATE; ++s)
            h[s] = __expf(dlt * A[s]) * h[s] + du * Bsh[t][s];
    }
    float* hp = hend + ((size_t)c * NCHAN + ch) * DSTATE;
    #pragma unroll
    for (int s = 0; s < DSTATE; ++s) hp[s] = h[s];
    sd[(size_t)c * NCHAN + ch] = sumd;
}

// Phase 2: thread = (channel,state). Sequential chunk combine; hend -> hin in place.
__global__ __launch_bounds__(256)
void scan_phase2(float* __restrict__ hbuf, const float* __restrict__ sd,
                 const float* __restrict__ A_log)
{
    int idx = blockIdx.x * 256 + threadIdx.x;   // < NCHAN*DSTATE
    int ch = idx >> 4, s = idx & 15;
    int d = ch & (DINNER - 1);
    float A = -__expf(A_log[(size_t)d * DSTATE + s]);
    float hrun = 0.f;
    for (int c = 0; c < NCH; ++c) {
        size_t o = (size_t)c * (NCHAN * DSTATE) + idx;
        float he  = hbuf[o];
        float sdv = sd[(size_t)c * NCHAN + ch];
        hbuf[o] = hrun;                      // now holds hin
        hrun = __expf(A * sdv) * hrun + he;
    }
}

// Phase 3: rescan from hin; y = sum_s h*C in-register; fused epilogue -> yy bf16.
__global__ __launch_bounds__(256)
void scan_phase3(const float* __restrict__ delta, const float* __restrict__ u,
                 const float* __restrict__ xdbl, const float* __restrict__ A_log,
                 const float* __restrict__ Dp, const float* __restrict__ xz,
                 const float* __restrict__ hin, unsigned short* __restrict__ yy)
{
    __shared__ float BC[CLEN][2 * DSTATE];
    int tid = threadIdx.x;
    int ch  = blockIdx.x * 256 + tid;
    int c   = blockIdx.y;
    int b   = ch >> 10;
    int d   = ch & (DINNER - 1);
    int row0 = b * T_SEQ + c * CLEN;
    {   // 256 threads stage 32 rows x 32 floats (B|C)
        int r = tid >> 3, col = (tid & 7) * 4;
        *(float4*)&BC[r][col] = *(const float4*)&xdbl[(size_t)(row0 + r) * 64 + DTRANK + col];
    }
    float A[DSTATE];
    const float* ap = A_log + (size_t)d * DSTATE;
    #pragma unroll
    for (int s = 0; s < DSTATE; ++s) A[s] = -__expf(ap[s]);
    float h[DSTATE];
    const float* hp = hin + ((size_t)c * NCHAN + ch) * DSTATE;
    #pragma unroll
    for (int s = 0; s < DSTATE; ++s) h[s] = hp[s];
    float Dval = Dp[d];
    __syncthreads();

    const float* dp = delta + (size_t)row0 * DINNER + d;
    const float* up = u     + (size_t)row0 * DINNER + d;
    const float* zp = xz    + (size_t)row0 * (2 * DINNER) + DINNER + d;
    unsigned short* yp = yy + (size_t)row0 * DINNER + d;
    for (int t = 0; t < CLEN; ++t) {
        float dlt = dp[(size_t)t * DINNER];
        float ut  = up[(size_t)t * DINNER];
        float du  = dlt * ut;
        float y0 = 0.f, y1 = 0.f;
        #pragma unroll
        for (int s = 0; s < DSTATE; s += 2) {
            h[s]     = __expf(dlt * A[s])     * h[s]     + du * BC[t][s];
            h[s + 1] = __expf(dlt * A[s + 1]) * h[s + 1] + du * BC[t][s + 1];
            y0 += h[s]     * BC[t][DSTATE + s];
            y1 += h[s + 1] * BC[t][DSTATE + s + 1];
        }
        float z = zp[(size_t)t * (2 * DINNER)];
        float sil = z / (1.f + __expf(-z));
        yp[(size_t)t * DINNER] = f2bf(((y0 + y1) + Dval * ut) * sil);
    }
}

// ---------------- masked mean pool ----------------
__global__ __launch_bounds__(512)
void pool_kernel(const float* __restrict__ h, const int* __restrict__ lengths,
                 float* __restrict__ pooled)
{
    int b  = blockIdx.x;
    int dm = threadIdx.x;
    int len = lengths[b];
    float cnt = fmaxf((float)len, 1.f);
    float acc = 0.f;
    for (int t = 0; t < len; ++t)
        acc += h[((size_t)b * T_SEQ + t) * DMODEL + dm];
    pooled[b * DMODEL + dm] = acc / cnt;
}

extern "C" void kernel_launch(void* const* d_in, const int* in_sizes, int n_in,
                              void* d_out, int out_size, void* d_ws, size_t ws_size,
                              hipStream_t stream)
{
    const float* x        = (const float*)d_in[0];
    const int*   lengths  = (const int*)d_in[1];
    const float* proj_w   = (const float*)d_in[2];
    const float* proj_b   = (const float*)d_in[3];
    const float* ln_w     = (const float*)d_in[4];
    const float* ln_b     = (const float*)d_in[5];
    const float* in_w     = (const float*)d_in[6];
    const float* conv_w   = (const float*)d_in[7];
    const float* conv_b   = (const float*)d_in[8];
    const float* xproj_w  = (const float*)d_in[9];
    const float* dtproj_w = (const float*)d_in[10];
    const float* dtproj_b = (const float*)d_in[11];
    const float* A_log    = (const float*)d_in[12];
    const float* Dp       = (const float*)d_in[13];
    const float* out_w    = (const float*)d_in[14];

    float* h      = (float*)d_out;                 // seq_out (8192x512)
    float* pooled = h + (size_t)MROWS * DMODEL;

    float* ws    = (float*)d_ws;
    float* xz    = ws;                                    // 16.78M f
    float* u     = xz    + (size_t)MROWS * 2 * DINNER;    // 8.39M f
    float* xdbl  = u     + (size_t)MROWS * DINNER;        // 0.52M f
    float* delta = xdbl  + (size_t)MROWS * 64;            // 8.39M f
    float* hbuf  = delta + (size_t)MROWS * DINNER;        // 32*8192*16 = 4.19M f
    float* sdbuf = hbuf  + (size_t)NCH * NCHAN * DSTATE;  // 32*8192 = 0.26M f
    unsigned short* hlnb  = (unsigned short*)(sdbuf + (size_t)NCH * NCHAN);
    unsigned short* yyb   = hlnb + (size_t)MROWS * DMODEL;
    unsigned short* inwT  = yyb  + (size_t)MROWS * DINNER;
    unsigned short* outwT = inwT + (size_t)NLAYER * DMODEL * 2 * DINNER;

    wconvT<<<dim3(2 * DINNER / 32, DMODEL / 32, NLAYER), 256, 0, stream>>>(in_w, inwT, DMODEL, 2 * DINNER);
    wconvT<<<dim3(DMODEL / 32, DINNER / 32, NLAYER), 256, 0, stream>>>(out_w, outwT, DINNER, DMODEL);

    // h = x @ proj_w + proj_b   (fp32; K=80)
    gemm_f32<1><<<dim3(DMODEL / BN, MROWS / BM), 256, 0, stream>>>(
        x, 80, proj_w, proj_b, h, DMODEL, MROWS, DMODEL, 80);

    for (int l = 0; l < NLAYER; ++l) {
        ln_kernel<<<MROWS, 256, 0, stream>>>(h, ln_w + l * DMODEL, ln_b + l * DMODEL, hlnb);

        // xz = h_ln @ in_w   (bf16 MFMA: M=8192, N=2048, K=512)
        gemm_mfma<0><<<dim3(2 * DINNER / 128, MROWS / 128), 256, 0, stream>>>(
            hlnb, inwT + (size_t)l * DMODEL * 2 * DINNER, xz, MROWS, 2 * DINNER, DMODEL);

        conv_silu<<<(MROWS * DINNER) / 256, 256, 0, stream>>>(
            xz, conv_w + l * DINNER * 3, conv_b + l * DINNER, u);

        // x_dbl = u @ xproj_w   (fp32: K=1024, N=64)
        gemm_f32<0><<<dim3(64 / BN, MROWS / BM), 256, 0, stream>>>(
            u, DINNER, xproj_w + (size_t)l * DINNER * 64, nullptr,
            xdbl, 64, MROWS, 64, DINNER);

        // delta = softplus(dt @ dtproj_w + dtproj_b)   (fp32: K=32, N=1024)
        gemm_f32<2><<<dim3(DINNER / BN, MROWS / BM), 256, 0, stream>>>(
            xdbl, 64, dtproj_w + (size_t)l * DTRANK * DINNER, dtproj_b + l * DINNER,
            delta, DINNER, MROWS, DINNER, DTRANK);

        // chunked selective scan (channel-per-thread)
        scan_phase1<<<dim3(NCHAN / 256, NCH), 256, 0, stream>>>(
            delta, u, xdbl, A_log + (size_t)l * DINNER * DSTATE, hbuf, sdbuf);
        scan_phase2<<<(NCHAN * DSTATE) / 256, 256, 0, stream>>>(
            hbuf, sdbuf, A_log + (size_t)l * DINNER * DSTATE);
        scan_phase3<<<dim3(NCHAN / 256, NCH), 256, 0, stream>>>(
            delta, u, xdbl, A_log + (size_t)l * DINNER * DSTATE, Dp + l * DINNER,
            xz, hbuf, yyb);

        // h += yy @ out_w   (bf16 MFMA: M=8192, N=512, K=1024, residual)
        gemm_mfma<3><<<dim3(DMODEL / 128, MROWS / 128), 256, 0, stream>>>(
            yyb, outwT + (size_t)l * DINNER * DMODEL, h, MROWS, DMODEL, DINNER);
    }

    pool_kernel<<<BATCH, DMODEL, 0, stream>>>(h, lengths, pooled);
}

// Round 5
// 979.737 us; speedup vs baseline: 5.2975x; 1.3048x over previous
//
#include <hip/hip_runtime.h>
#include <math.h>

#define T_SEQ   1024
#define BATCH   8
#define DMODEL  512
#define DINNER  1024
#define DSTATE  16
#define DTRANK  32
#define NLAYER  4
#define MROWS   (BATCH * T_SEQ)   // 8192
#define NCH     32                // scan chunks
#define CLEN    (T_SEQ / NCH)     // 32
#define NCHAN   (BATCH * DINNER)  // 8192 channels
#define PCHUNK  16                // pool t-chunks

typedef float f32x4 __attribute__((ext_vector_type(4)));
typedef short s16x8 __attribute__((ext_vector_type(8)));

__device__ __forceinline__ unsigned short f2bf(float f) {
    unsigned u = __builtin_bit_cast(unsigned, f);
    u = (u + 0x7FFFu + ((u >> 16) & 1u)) >> 16;
    return (unsigned short)u;
}

// ---------------- bf16 MFMA GEMM (128x128 tile) ----------------
// C[M,N] fp32 = A[M,K] bf16 @ B^T[N,K] bf16.
// EPI 0: store; 2: softplus(x + bias[n]); 3: C += acc (residual).
template<int EPI>
__global__ __launch_bounds__(256)
void gemm_mfma(const unsigned short* __restrict__ A,
               const unsigned short* __restrict__ BT,
               const float* __restrict__ bias,
               float* __restrict__ C, int M, int N, int K)
{
    __shared__ __align__(16) unsigned short As[128 * 32];
    __shared__ __align__(16) unsigned short Bs[128 * 32];
    const int tid  = threadIdx.x;
    const int bn   = blockIdx.x * 128;
    const int bm   = blockIdx.y * 128;
    const int wave = tid >> 6;
    const int lane = tid & 63;
    const int wm = (wave >> 1) * 64;
    const int wn = (wave & 1) * 64;

    #define UNIT(row, kg) ((((row) << 2) | (kg)) ^ ((row) & 7))

    const int srow = tid >> 2;
    const int skg  = tid & 3;
    const int u0 = UNIT(srow, skg);
    const int u1 = UNIT(srow + 64, skg);

    const int r15 = lane & 15;
    const int kgl = lane >> 4;
    int aoff[4], boff[4];
    #pragma unroll
    for (int i = 0; i < 4; ++i) {
        aoff[i] = UNIT(wm + i * 16 + r15, kgl) * 8;
        boff[i] = UNIT(wn + i * 16 + r15, kgl) * 8;
    }

    const unsigned short* Ap0 = A  + (size_t)(bm + srow)      * K + skg * 8;
    const unsigned short* Ap1 = A  + (size_t)(bm + srow + 64) * K + skg * 8;
    const unsigned short* Bp0 = BT + (size_t)(bn + srow)      * K + skg * 8;
    const unsigned short* Bp1 = BT + (size_t)(bn + srow + 64) * K + skg * 8;

    f32x4 zero = {0.f, 0.f, 0.f, 0.f};
    f32x4 acc[4][4];
    #pragma unroll
    for (int i = 0; i < 4; ++i)
        #pragma unroll
        for (int j = 0; j < 4; ++j) acc[i][j] = zero;

    for (int k0 = 0; k0 < K; k0 += 32) {
        uint4 a0 = *(const uint4*)(Ap0 + k0);
        uint4 a1 = *(const uint4*)(Ap1 + k0);
        uint4 b0 = *(const uint4*)(Bp0 + k0);
        uint4 b1 = *(const uint4*)(Bp1 + k0);
        __syncthreads();
        *(uint4*)(As + u0 * 8) = a0;
        *(uint4*)(As + u1 * 8) = a1;
        *(uint4*)(Bs + u0 * 8) = b0;
        *(uint4*)(Bs + u1 * 8) = b1;
        __syncthreads();
        s16x8 fa[4], fb[4];
        #pragma unroll
        for (int i = 0; i < 4; ++i) {
            fa[i] = *(const s16x8*)(As + aoff[i]);
            fb[i] = *(const s16x8*)(Bs + boff[i]);
        }
        #pragma unroll
        for (int mi = 0; mi < 4; ++mi)
            #pragma unroll
            for (int ni = 0; ni < 4; ++ni)
                acc[mi][ni] = __builtin_amdgcn_mfma_f32_16x16x32_bf16(
                    fa[mi], fb[ni], acc[mi][ni], 0, 0, 0);
    }

    #pragma unroll
    for (int mi = 0; mi < 4; ++mi) {
        #pragma unroll
        for (int j = 0; j < 4; ++j) {
            int row = bm + wm + mi * 16 + kgl * 4 + j;
            float* cp = &C[(size_t)row * N + bn + wn + r15];
            #pragma unroll
            for (int ni = 0; ni < 4; ++ni) {
                float v = acc[mi][ni][j];
                if (EPI == 2) {
                    v += bias[bn + wn + ni * 16 + r15];
                    v = (v > 20.f) ? v : log1pf(__expf(v));
                }
                if (EPI == 3) v += cp[ni * 16];
                cp[ni * 16] = v;
            }
        }
    }
    #undef UNIT
}

// ---------------- bf16 MFMA GEMM, N=64 (128x64 tile) ----------------
// 4 waves x (32 rows x 64 cols); for xdbl = u @ xproj_w.
__global__ __launch_bounds__(256)
void gemm_mfma_n64(const unsigned short* __restrict__ A,
                   const unsigned short* __restrict__ BT,
                   float* __restrict__ C, int M, int K)
{
    __shared__ __align__(16) unsigned short As[128 * 32];
    __shared__ __align__(16) unsigned short Bs[64 * 32];
    const int tid  = threadIdx.x;
    const int bm   = blockIdx.y * 128;
    const int wave = tid >> 6;
    const int lane = tid & 63;
    const int wm = wave * 32;

    #define UNIT(row, kg) ((((row) << 2) | (kg)) ^ ((row) & 7))
    const int srow = tid >> 2;       // 0..63
    const int skg  = tid & 3;
    const int u0 = UNIT(srow, skg);
    const int u1 = UNIT(srow + 64, skg);

    const int r15 = lane & 15;
    const int kgl = lane >> 4;
    int aoff[2], boff[4];
    #pragma unroll
    for (int i = 0; i < 2; ++i) aoff[i] = UNIT(wm + i * 16 + r15, kgl) * 8;
    #pragma unroll
    for (int i = 0; i < 4; ++i) boff[i] = UNIT(i * 16 + r15, kgl) * 8;

    const unsigned short* Ap0 = A  + (size_t)(bm + srow)      * K + skg * 8;
    const unsigned short* Ap1 = A  + (size_t)(bm + srow + 64) * K + skg * 8;
    const unsigned short* Bp  = BT + (size_t)srow             * K + skg * 8;

    f32x4 zero = {0.f, 0.f, 0.f, 0.f};
    f32x4 acc[2][4];
    #pragma unroll
    for (int i = 0; i < 2; ++i)
        #pragma unroll
        for (int j = 0; j < 4; ++j) acc[i][j] = zero;

    for (int k0 = 0; k0 < K; k0 += 32) {
        uint4 a0 = *(const uint4*)(Ap0 + k0);
        uint4 a1 = *(const uint4*)(Ap1 + k0);
        uint4 b0 = *(const uint4*)(Bp  + k0);
        __syncthreads();
        *(uint4*)(As + u0 * 8) = a0;
        *(uint4*)(As + u1 * 8) = a1;
        *(uint4*)(Bs + u0 * 8) = b0;
        __syncthreads();
        s16x8 fa[2], fb[4];
        #pragma unroll
        for (int i = 0; i < 2; ++i) fa[i] = *(const s16x8*)(As + aoff[i]);
        #pragma unroll
        for (int i = 0; i < 4; ++i) fb[i] = *(const s16x8*)(Bs + boff[i]);
        #pragma unroll
        for (int mi = 0; mi < 2; ++mi)
            #pragma unroll
            for (int ni = 0; ni < 4; ++ni)
                acc[mi][ni] = __builtin_amdgcn_mfma_f32_16x16x32_bf16(
                    fa[mi], fb[ni], acc[mi][ni], 0, 0, 0);
    }

    #pragma unroll
    for (int mi = 0; mi < 2; ++mi) {
        #pragma unroll
        for (int j = 0; j < 4; ++j) {
            int row = bm + wm + mi * 16 + kgl * 4 + j;
            float* cp = &C[(size_t)row * 64 + r15];
            #pragma unroll
            for (int ni = 0; ni < 4; ++ni)
                cp[ni * 16] = acc[mi][ni][j];
        }
    }
    #undef UNIT
}

// ---------------- weight transpose + fp32->bf16 ----------------
// src: [L][R][Cc] fp32  ->  dst: [L][Cc][R] bf16
__global__ __launch_bounds__(256)
void wconvT(const float* __restrict__ W, unsigned short* __restrict__ WT,
            int R, int Cc)
{
    int l = blockIdx.z;
    const float* src = W + (size_t)l * R * Cc;
    unsigned short* dst = WT + (size_t)l * R * Cc;
    __shared__ float tile[32][33];
    int c0 = blockIdx.x * 32, r0 = blockIdx.y * 32;
    int tx = threadIdx.x & 31, ty = threadIdx.x >> 5;
    #pragma unroll
    for (int i = 0; i < 4; ++i)
        tile[ty + i * 8][tx] = src[(size_t)(r0 + ty + i * 8) * Cc + c0 + tx];
    __syncthreads();
    #pragma unroll
    for (int i = 0; i < 4; ++i)
        dst[(size_t)(c0 + ty + i * 8) * R + r0 + tx] = f2bf(tile[tx][ty + i * 8]);
}

// ---------------- generic tiled fp32 GEMM (input proj only) ----------------
#define BM 64
#define BN 64
#define BK 16

template<int EPI>
__global__ __launch_bounds__(256)
void gemm_f32(const float* __restrict__ A, int lda,
              const float* __restrict__ B,
              const float* __restrict__ bias,
              float* __restrict__ C, int ldc,
              int M, int N, int K)
{
    __shared__ float As[BK][BM];
    __shared__ float Bs[BK][BN];
    const int bn = blockIdx.x * BN;
    const int bm = blockIdx.y * BM;
    const int tid = threadIdx.x;
    const int tx = tid & 15;
    const int ty = tid >> 4;
    const int ar = tid >> 2;
    const int ac = (tid & 3) * 4;
    const int br = tid >> 4;
    const int bc = (tid & 15) * 4;

    float acc[4][4] = {};

    for (int k0 = 0; k0 < K; k0 += BK) {
        float4 av = *(const float4*)&A[(bm + ar) * lda + k0 + ac];
        float4 bv = *(const float4*)&B[(k0 + br) * N + bn + bc];
        As[ac + 0][ar] = av.x;
        As[ac + 1][ar] = av.y;
        As[ac + 2][ar] = av.z;
        As[ac + 3][ar] = av.w;
        *(float4*)&Bs[br][bc] = bv;
        __syncthreads();
        #pragma unroll
        for (int kk = 0; kk < BK; ++kk) {
            float4 a = *(const float4*)&As[kk][ty * 4];
            float4 b = *(const float4*)&Bs[kk][tx * 4];
            float af[4] = {a.x, a.y, a.z, a.w};
            float bfv[4] = {b.x, b.y, b.z, b.w};
            #pragma unroll
            for (int i = 0; i < 4; ++i)
                #pragma unroll
                for (int j = 0; j < 4; ++j)
                    acc[i][j] = fmaf(af[i], bfv[j], acc[i][j]);
        }
        __syncthreads();
    }

    #pragma unroll
    for (int i = 0; i < 4; ++i) {
        int r = bm + ty * 4 + i;
        float* cp = &C[r * ldc + bn + tx * 4];
        float v[4];
        #pragma unroll
        for (int j = 0; j < 4; ++j) {
            float xv = acc[i][j];
            if (EPI == 1) xv += bias[bn + tx * 4 + j];
            v[j] = xv;
        }
        float4 o; o.x = v[0]; o.y = v[1]; o.z = v[2]; o.w = v[3];
        *(float4*)cp = o;
    }
}

// ---------------- LayerNorm -> bf16 ----------------
__global__ __launch_bounds__(256)
void ln_kernel(const float* __restrict__ x, const float* __restrict__ w,
               const float* __restrict__ b, unsigned short* __restrict__ out)
{
    int row = blockIdx.x;
    const float* xr = x + (size_t)row * DMODEL;
    int tid = threadIdx.x;
    float2 v = ((const float2*)xr)[tid];
    float s  = v.x + v.y;
    float sq = v.x * v.x + v.y * v.y;
    #pragma unroll
    for (int off = 32; off > 0; off >>= 1) {
        s  += __shfl_down(s, off);
        sq += __shfl_down(sq, off);
    }
    __shared__ float ss[4], ssq[4];
    if ((tid & 63) == 0) { ss[tid >> 6] = s; ssq[tid >> 6] = sq; }
    __syncthreads();
    s  = ss[0] + ss[1] + ss[2] + ss[3];
    sq = ssq[0] + ssq[1] + ssq[2] + ssq[3];
    float mu  = s * (1.f / DMODEL);
    float var = sq * (1.f / DMODEL) - mu * mu;
    float rs  = rsqrtf(var + 1e-5f);
    float2 wv = ((const float2*)w)[tid];
    float2 bv = ((const float2*)b)[tid];
    float o0 = (v.x - mu) * rs * wv.x + bv.x;
    float o1 = (v.y - mu) * rs * wv.y + bv.y;
    unsigned pack = (unsigned)f2bf(o0) | ((unsigned)f2bf(o1) << 16);
    ((unsigned*)(out + (size_t)row * DMODEL))[tid] = pack;
}

// ---------------- depthwise causal conv(3) + silu (fp32 + bf16 out) ----------------
__global__ __launch_bounds__(256)
void conv_silu(const float* __restrict__ xz, const float* __restrict__ cw,
               const float* __restrict__ cb, float* __restrict__ u,
               unsigned short* __restrict__ ubf)
{
    int idx = blockIdx.x * 256 + threadIdx.x;
    int d   = idx & (DINNER - 1);
    int row = idx >> 10;
    int t   = row & (T_SEQ - 1);
    float acc = cb[d];
    #pragma unroll
    for (int k = 0; k < 3; ++k) {
        int tt = t - 2 + k;
        if (tt >= 0)
            acc += xz[(size_t)(row - 2 + k) * (2 * DINNER) + d] * cw[d * 3 + k];
    }
    float val = acc / (1.f + __expf(-acc));
    u[(size_t)row * DINNER + d] = val;
    ubf[(size_t)row * DINNER + d] = f2bf(val);
}

// ---------------- dt (xdbl[:, :32]) -> bf16 ----------------
__global__ __launch_bounds__(256)
void dt2bf(const float* __restrict__ xdbl, unsigned short* __restrict__ dtb)
{
    int idx = blockIdx.x * 256 + threadIdx.x;   // < MROWS*32
    int row = idx >> 5, col = idx & 31;
    dtb[idx] = f2bf(xdbl[(size_t)row * 64 + col]);
}

// ---------------- chunked selective scan (channel-per-thread) ----------------
__global__ __launch_bounds__(256)
void scan_phase1(const float* __restrict__ delta, const float* __restrict__ u,
                 const float* __restrict__ xdbl, const float* __restrict__ A_log,
                 float* __restrict__ hend, float* __restrict__ sd)
{
    __shared__ float Bsh[CLEN][DSTATE];
    int tid = threadIdx.x;
    int ch  = blockIdx.x * 256 + tid;
    int c   = blockIdx.y;
    int b   = ch >> 10;
    int d   = ch & (DINNER - 1);
    int row0 = b * T_SEQ + c * CLEN;
    if (tid < CLEN * DSTATE / 4) {
        int r = tid >> 2, col = (tid & 3) * 4;
        *(float4*)&Bsh[r][col] = *(const float4*)&xdbl[(size_t)(row0 + r) * 64 + DTRANK + col];
    }
    float A[DSTATE];
    const float* ap = A_log + (size_t)d * DSTATE;
    #pragma unroll
    for (int s = 0; s < DSTATE; ++s) A[s] = -__expf(ap[s]);
    __syncthreads();

    float h[DSTATE];
    #pragma unroll
    for (int s = 0; s < DSTATE; ++s) h[s] = 0.f;
    float sumd = 0.f;
    const float* dp = delta + (size_t)row0 * DINNER + d;
    const float* up = u     + (size_t)row0 * DINNER + d;
    for (int t = 0; t < CLEN; ++t) {
        float dlt = dp[(size_t)t * DINNER];
        float ut  = up[(size_t)t * DINNER];
        float du  = dlt * ut;
        sumd += dlt;
        #pragma unroll
        for (int s = 0; s < DSTATE; ++s)
            h[s] = __expf(dlt * A[s]) * h[s] + du * Bsh[t][s];
    }
    float* hp = hend + ((size_t)c * NCHAN + ch) * DSTATE;
    #pragma unroll
    for (int s = 0; s < DSTATE; ++s) hp[s] = h[s];
    sd[(size_t)c * NCHAN + ch] = sumd;
}

__global__ __launch_bounds__(256)
void scan_phase2(float* __restrict__ hbuf, const float* __restrict__ sd,
                 const float* __restrict__ A_log)
{
    int idx = blockIdx.x * 256 + threadIdx.x;
    int ch = idx >> 4, s = idx & 15;
    int d = ch & (DINNER - 1);
    float A = -__expf(A_log[(size_t)d * DSTATE + s]);
    float hrun = 0.f;
    for (int c = 0; c < NCH; ++c) {
        size_t o = (size_t)c * (NCHAN * DSTATE) + idx;
        float he  = hbuf[o];
        float sdv = sd[(size_t)c * NCHAN + ch];
        hbuf[o] = hrun;
        hrun = __expf(A * sdv) * hrun + he;
    }
}

__global__ __launch_bounds__(256)
void scan_phase3(const float* __restrict__ delta, const float* __restrict__ u,
                 const float* __restrict__ xdbl, const float* __restrict__ A_log,
                 const float* __restrict__ Dp, const float* __restrict__ xz,
                 const float* __restrict__ hin, unsigned short* __restrict__ yy)
{
    __shared__ float BC[CLEN][2 * DSTATE];
    int tid = threadIdx.x;
    int ch  = blockIdx.x * 256 + tid;
    int c   = blockIdx.y;
    int b   = ch >> 10;
    int d   = ch & (DINNER - 1);
    int row0 = b * T_SEQ + c * CLEN;
    {
        int r = tid >> 3, col = (tid & 7) * 4;
        *(float4*)&BC[r][col] = *(const float4*)&xdbl[(size_t)(row0 + r) * 64 + DTRANK + col];
    }
    float A[DSTATE];
    const float* ap = A_log + (size_t)d * DSTATE;
    #pragma unroll
    for (int s = 0; s < DSTATE; ++s) A[s] = -__expf(ap[s]);
    float h[DSTATE];
    const float* hp = hin + ((size_t)c * NCHAN + ch) * DSTATE;
    #pragma unroll
    for (int s = 0; s < DSTATE; ++s) h[s] = hp[s];
    float Dval = Dp[d];
    __syncthreads();

    const float* dp = delta + (size_t)row0 * DINNER + d;
    const float* up = u     + (size_t)row0 * DINNER + d;
    const float* zp = xz    + (size_t)row0 * (2 * DINNER) + DINNER + d;
    unsigned short* yp = yy + (size_t)row0 * DINNER + d;
    for (int t = 0; t < CLEN; ++t) {
        float dlt = dp[(size_t)t * DINNER];
        float ut  = up[(size_t)t * DINNER];
        float du  = dlt * ut;
        float y0 = 0.f, y1 = 0.f;
        #pragma unroll
        for (int s = 0; s < DSTATE; s += 2) {
            h[s]     = __expf(dlt * A[s])     * h[s]     + du * BC[t][s];
            h[s + 1] = __expf(dlt * A[s + 1]) * h[s + 1] + du * BC[t][s + 1];
            y0 += h[s]     * BC[t][DSTATE + s];
            y1 += h[s + 1] * BC[t][DSTATE + s + 1];
        }
        float z = zp[(size_t)t * (2 * DINNER)];
        float sil = z / (1.f + __expf(-z));
        yp[(size_t)t * DINNER] = f2bf(((y0 + y1) + Dval * ut) * sil);
    }
}

// ---------------- masked mean pool (two-stage) ----------------
__global__ __launch_bounds__(512)
void pool_partial(const float* __restrict__ h, const int* __restrict__ lengths,
                  float* __restrict__ ppart)
{
    int b  = blockIdx.x;
    int ck = blockIdx.y;
    int dm = threadIdx.x;
    int len = lengths[b];
    int t0 = ck * (T_SEQ / PCHUNK);
    int t1 = t0 + (T_SEQ / PCHUNK);
    if (t1 > len) t1 = len;
    float acc = 0.f;
    for (int t = t0; t < t1; ++t)
        acc += h[((size_t)b * T_SEQ + t) * DMODEL + dm];
    ppart[((size_t)b * PCHUNK + ck) * DMODEL + dm] = acc;
}

__global__ __launch_bounds__(512)
void pool_final(const float* __restrict__ ppart, const int* __restrict__ lengths,
                float* __restrict__ pooled)
{
    int b  = blockIdx.x;
    int dm = threadIdx.x;
    float acc = 0.f;
    #pragma unroll
    for (int ck = 0; ck < PCHUNK; ++ck)
        acc += ppart[((size_t)b * PCHUNK + ck) * DMODEL + dm];
    pooled[b * DMODEL + dm] = acc / fmaxf((float)lengths[b], 1.f);
}

extern "C" void kernel_launch(void* const* d_in, const int* in_sizes, int n_in,
                              void* d_out, int out_size, void* d_ws, size_t ws_size,
                              hipStream_t stream)
{
    const float* x        = (const float*)d_in[0];
    const int*   lengths  = (const int*)d_in[1];
    const float* proj_w   = (const float*)d_in[2];
    const float* proj_b   = (const float*)d_in[3];
    const float* ln_w     = (const float*)d_in[4];
    const float* ln_b     = (const float*)d_in[5];
    const float* in_w     = (const float*)d_in[6];
    const float* conv_w   = (const float*)d_in[7];
    const float* conv_b   = (const float*)d_in[8];
    const float* xproj_w  = (const float*)d_in[9];
    const float* dtproj_w = (const float*)d_in[10];
    const float* dtproj_b = (const float*)d_in[11];
    const float* A_log    = (const float*)d_in[12];
    const float* Dp       = (const float*)d_in[13];
    const float* out_w    = (const float*)d_in[14];

    float* h      = (float*)d_out;                 // seq_out (8192x512)
    float* pooled = h + (size_t)MROWS * DMODEL;

    float* ws    = (float*)d_ws;
    float* xz    = ws;                                    // 16.78M f
    float* u     = xz    + (size_t)MROWS * 2 * DINNER;    // 8.39M f
    float* xdbl  = u     + (size_t)MROWS * DINNER;        // 0.52M f
    float* delta = xdbl  + (size_t)MROWS * 64;            // 8.39M f
    float* hbuf  = delta + (size_t)MROWS * DINNER;        // 4.19M f
    float* sdbuf = hbuf  + (size_t)NCH * NCHAN * DSTATE;  // 0.26M f
    unsigned short* hlnb    = (unsigned short*)(sdbuf + (size_t)NCH * NCHAN);
    unsigned short* yyb     = hlnb    + (size_t)MROWS * DMODEL;
    unsigned short* inwT    = yyb     + (size_t)MROWS * DINNER;
    unsigned short* outwT   = inwT    + (size_t)NLAYER * DMODEL * 2 * DINNER;
    unsigned short* xprojT  = outwT   + (size_t)NLAYER * DINNER * DMODEL;
    unsigned short* dtprojT = xprojT  + (size_t)NLAYER * 64 * DINNER;
    unsigned short* dtbf    = dtprojT + (size_t)NLAYER * DTRANK * DINNER;
    float* ppart = (float*)(dtbf + (size_t)MROWS * DTRANK);   // 8*16*512 f
    // ubf (bf16 u) aliases delta: live window conv->xproj precedes delta's write.
    unsigned short* ubf = (unsigned short*)delta;

    // Weight prep
    wconvT<<<dim3(2 * DINNER / 32, DMODEL / 32, NLAYER), 256, 0, stream>>>(in_w, inwT, DMODEL, 2 * DINNER);
    wconvT<<<dim3(DMODEL / 32, DINNER / 32, NLAYER), 256, 0, stream>>>(out_w, outwT, DINNER, DMODEL);
    wconvT<<<dim3(64 / 32, DINNER / 32, NLAYER), 256, 0, stream>>>(xproj_w, xprojT, DINNER, 64);
    wconvT<<<dim3(DINNER / 32, DTRANK / 32, NLAYER), 256, 0, stream>>>(dtproj_w, dtprojT, DTRANK, DINNER);

    // h = x @ proj_w + proj_b   (fp32; K=80)
    gemm_f32<1><<<dim3(DMODEL / BN, MROWS / BM), 256, 0, stream>>>(
        x, 80, proj_w, proj_b, h, DMODEL, MROWS, DMODEL, 80);

    for (int l = 0; l < NLAYER; ++l) {
        ln_kernel<<<MROWS, 256, 0, stream>>>(h, ln_w + l * DMODEL, ln_b + l * DMODEL, hlnb);

        // xz = h_ln @ in_w   (MFMA: M=8192, N=2048, K=512)
        gemm_mfma<0><<<dim3(2 * DINNER / 128, MROWS / 128), 256, 0, stream>>>(
            hlnb, inwT + (size_t)l * DMODEL * 2 * DINNER, nullptr, xz, MROWS, 2 * DINNER, DMODEL);

        conv_silu<<<(MROWS * DINNER) / 256, 256, 0, stream>>>(
            xz, conv_w + l * DINNER * 3, conv_b + l * DINNER, u, ubf);

        // x_dbl = u @ xproj_w   (MFMA: M=8192, N=64, K=1024)
        gemm_mfma_n64<<<dim3(1, MROWS / 128), 256, 0, stream>>>(
            ubf, xprojT + (size_t)l * 64 * DINNER, xdbl, MROWS, DINNER);

        dt2bf<<<(MROWS * DTRANK) / 256, 256, 0, stream>>>(xdbl, dtbf);

        // delta = softplus(dt @ dtproj_w + dtproj_b)   (MFMA: M=8192, N=1024, K=32)
        gemm_mfma<2><<<dim3(DINNER / 128, MROWS / 128), 256, 0, stream>>>(
            dtbf, dtprojT + (size_t)l * DTRANK * DINNER, dtproj_b + l * DINNER,
            delta, MROWS, DINNER, DTRANK);

        // chunked selective scan
        scan_phase1<<<dim3(NCHAN / 256, NCH), 256, 0, stream>>>(
            delta, u, xdbl, A_log + (size_t)l * DINNER * DSTATE, hbuf, sdbuf);
        scan_phase2<<<(NCHAN * DSTATE) / 256, 256, 0, stream>>>(
            hbuf, sdbuf, A_log + (size_t)l * DINNER * DSTATE);
        scan_phase3<<<dim3(NCHAN / 256, NCH), 256, 0, stream>>>(
            delta, u, xdbl, A_log + (size_t)l * DINNER * DSTATE, Dp + l * DINNER,
            xz, hbuf, yyb);

        // h += yy @ out_w   (MFMA: M=8192, N=512, K=1024, residual)
        gemm_mfma<3><<<dim3(DMODEL / 128, MROWS / 128), 256, 0, stream>>>(
            yyb, outwT + (size_t)l * DINNER * DMODEL, nullptr, h, MROWS, DMODEL, DINNER);
    }

    pool_partial<<<dim3(BATCH, PCHUNK), 512, 0, stream>>>(h, lengths, ppart);
    pool_final<<<BATCH, 512, 0, stream>>>(ppart, lengths, pooled);
}

// Round 6
// 955.267 us; speedup vs baseline: 5.4333x; 1.0256x over previous
//
#include <hip/hip_runtime.h>
#include <math.h>

#define T_SEQ   1024
#define BATCH   8
#define DMODEL  512
#define DINNER  1024
#define DSTATE  16
#define DTRANK  32
#define NLAYER  4
#define MROWS   (BATCH * T_SEQ)   // 8192
#define NCH     32                // scan chunks
#define CLEN    (T_SEQ / NCH)     // 32
#define NCHAN   (BATCH * DINNER)  // 8192 channels
#define PCHUNK  16                // pool t-chunks

typedef float f32x4 __attribute__((ext_vector_type(4)));
typedef short s16x8 __attribute__((ext_vector_type(8)));

__device__ __forceinline__ unsigned short f2bf(float f) {
    unsigned u = __builtin_bit_cast(unsigned, f);
    u = (u + 0x7FFFu + ((u >> 16) & 1u)) >> 16;
    return (unsigned short)u;
}
__device__ __forceinline__ float bf2f(unsigned short v) {
    unsigned u = ((unsigned)v) << 16;
    return __builtin_bit_cast(float, u);
}

// ---------------- bf16 MFMA GEMM (128x128 tile) ----------------
// C[M,N] = A[M,K] bf16 @ B^T[N,K] bf16.
// EPI 0: plain store; 2: softplus(x + bias[n]); 3: fp32 C += acc (residual).
// BF16OUT: write bf16 (EPI 0/2 only).
template<int EPI, bool BF16OUT>
__global__ __launch_bounds__(256)
void gemm_mfma(const unsigned short* __restrict__ A,
               const unsigned short* __restrict__ BT,
               const float* __restrict__ bias,
               void* __restrict__ Cv, int M, int N, int K)
{
    __shared__ __align__(16) unsigned short As[128 * 32];
    __shared__ __align__(16) unsigned short Bs[128 * 32];
    const int tid  = threadIdx.x;
    const int bn   = blockIdx.x * 128;
    const int bm   = blockIdx.y * 128;
    const int wave = tid >> 6;
    const int lane = tid & 63;
    const int wm = (wave >> 1) * 64;
    const int wn = (wave & 1) * 64;

    #define UNIT(row, kg) ((((row) << 2) | (kg)) ^ ((row) & 7))

    const int srow = tid >> 2;
    const int skg  = tid & 3;
    const int u0 = UNIT(srow, skg);
    const int u1 = UNIT(srow + 64, skg);

    const int r15 = lane & 15;
    const int kgl = lane >> 4;
    int aoff[4], boff[4];
    #pragma unroll
    for (int i = 0; i < 4; ++i) {
        aoff[i] = UNIT(wm + i * 16 + r15, kgl) * 8;
        boff[i] = UNIT(wn + i * 16 + r15, kgl) * 8;
    }

    const unsigned short* Ap0 = A  + (size_t)(bm + srow)      * K + skg * 8;
    const unsigned short* Ap1 = A  + (size_t)(bm + srow + 64) * K + skg * 8;
    const unsigned short* Bp0 = BT + (size_t)(bn + srow)      * K + skg * 8;
    const unsigned short* Bp1 = BT + (size_t)(bn + srow + 64) * K + skg * 8;

    f32x4 zero = {0.f, 0.f, 0.f, 0.f};
    f32x4 acc[4][4];
    #pragma unroll
    for (int i = 0; i < 4; ++i)
        #pragma unroll
        for (int j = 0; j < 4; ++j) acc[i][j] = zero;

    for (int k0 = 0; k0 < K; k0 += 32) {
        uint4 a0 = *(const uint4*)(Ap0 + k0);
        uint4 a1 = *(const uint4*)(Ap1 + k0);
        uint4 b0 = *(const uint4*)(Bp0 + k0);
        uint4 b1 = *(const uint4*)(Bp1 + k0);
        __syncthreads();
        *(uint4*)(As + u0 * 8) = a0;
        *(uint4*)(As + u1 * 8) = a1;
        *(uint4*)(Bs + u0 * 8) = b0;
        *(uint4*)(Bs + u1 * 8) = b1;
        __syncthreads();
        s16x8 fa[4], fb[4];
        #pragma unroll
        for (int i = 0; i < 4; ++i) {
            fa[i] = *(const s16x8*)(As + aoff[i]);
            fb[i] = *(const s16x8*)(Bs + boff[i]);
        }
        #pragma unroll
        for (int mi = 0; mi < 4; ++mi)
            #pragma unroll
            for (int ni = 0; ni < 4; ++ni)
                acc[mi][ni] = __builtin_amdgcn_mfma_f32_16x16x32_bf16(
                    fa[mi], fb[ni], acc[mi][ni], 0, 0, 0);
    }

    #pragma unroll
    for (int mi = 0; mi < 4; ++mi) {
        #pragma unroll
        for (int j = 0; j < 4; ++j) {
            int row = bm + wm + mi * 16 + kgl * 4 + j;
            #pragma unroll
            for (int ni = 0; ni < 4; ++ni) {
                float v = acc[mi][ni][j];
                int col = bn + wn + ni * 16 + r15;
                if (EPI == 2) {
                    v += bias[col];
                    v = (v > 20.f) ? v : log1pf(__expf(v));
                }
                if (BF16OUT) {
                    ((unsigned short*)Cv)[(size_t)row * N + col] = f2bf(v);
                } else {
                    float* cp = (float*)Cv + (size_t)row * N + col;
                    if (EPI == 3) v += *cp;
                    *cp = v;
                }
            }
        }
    }
    #undef UNIT
}

// ---------------- bf16 MFMA GEMM, N=64 (128x64 tile) ----------------
// xdbl = u @ xproj_w -> fp32 xdbl; also emits bf16 dt (cols 0..31).
__global__ __launch_bounds__(256)
void gemm_mfma_n64(const unsigned short* __restrict__ A,
                   const unsigned short* __restrict__ BT,
                   float* __restrict__ C, unsigned short* __restrict__ dtb,
                   int M, int K)
{
    __shared__ __align__(16) unsigned short As[128 * 32];
    __shared__ __align__(16) unsigned short Bs[64 * 32];
    const int tid  = threadIdx.x;
    const int bm   = blockIdx.y * 128;
    const int wave = tid >> 6;
    const int lane = tid & 63;
    const int wm = wave * 32;

    #define UNIT(row, kg) ((((row) << 2) | (kg)) ^ ((row) & 7))
    const int srow = tid >> 2;
    const int skg  = tid & 3;
    const int u0 = UNIT(srow, skg);
    const int u1 = UNIT(srow + 64, skg);

    const int r15 = lane & 15;
    const int kgl = lane >> 4;
    int aoff[2], boff[4];
    #pragma unroll
    for (int i = 0; i < 2; ++i) aoff[i] = UNIT(wm + i * 16 + r15, kgl) * 8;
    #pragma unroll
    for (int i = 0; i < 4; ++i) boff[i] = UNIT(i * 16 + r15, kgl) * 8;

    const unsigned short* Ap0 = A  + (size_t)(bm + srow)      * K + skg * 8;
    const unsigned short* Ap1 = A  + (size_t)(bm + srow + 64) * K + skg * 8;
    const unsigned short* Bp  = BT + (size_t)srow             * K + skg * 8;

    f32x4 zero = {0.f, 0.f, 0.f, 0.f};
    f32x4 acc[2][4];
    #pragma unroll
    for (int i = 0; i < 2; ++i)
        #pragma unroll
        for (int j = 0; j < 4; ++j) acc[i][j] = zero;

    for (int k0 = 0; k0 < K; k0 += 32) {
        uint4 a0 = *(const uint4*)(Ap0 + k0);
        uint4 a1 = *(const uint4*)(Ap1 + k0);
        uint4 b0 = *(const uint4*)(Bp  + k0);
        __syncthreads();
        *(uint4*)(As + u0 * 8) = a0;
        *(uint4*)(As + u1 * 8) = a1;
        *(uint4*)(Bs + u0 * 8) = b0;
        __syncthreads();
        s16x8 fa[2], fb[4];
        #pragma unroll
        for (int i = 0; i < 2; ++i) fa[i] = *(const s16x8*)(As + aoff[i]);
        #pragma unroll
        for (int i = 0; i < 4; ++i) fb[i] = *(const s16x8*)(Bs + boff[i]);
        #pragma unroll
        for (int mi = 0; mi < 2; ++mi)
            #pragma unroll
            for (int ni = 0; ni < 4; ++ni)
                acc[mi][ni] = __builtin_amdgcn_mfma_f32_16x16x32_bf16(
                    fa[mi], fb[ni], acc[mi][ni], 0, 0, 0);
    }

    #pragma unroll
    for (int mi = 0; mi < 2; ++mi) {
        #pragma unroll
        for (int j = 0; j < 4; ++j) {
            int row = bm + wm + mi * 16 + kgl * 4 + j;
            float* cp = &C[(size_t)row * 64 + r15];
            #pragma unroll
            for (int ni = 0; ni < 4; ++ni) {
                float v = acc[mi][ni][j];
                cp[ni * 16] = v;
                if (ni < 2)   // dt = cols 0..31 -> bf16
                    dtb[(size_t)row * DTRANK + ni * 16 + r15] = f2bf(v);
            }
        }
    }
    #undef UNIT
}

// ---------------- weight transpose + fp32->bf16 ----------------
__global__ __launch_bounds__(256)
void wconvT(const float* __restrict__ W, unsigned short* __restrict__ WT,
            int R, int Cc)
{
    int l = blockIdx.z;
    const float* src = W + (size_t)l * R * Cc;
    unsigned short* dst = WT + (size_t)l * R * Cc;
    __shared__ float tile[32][33];
    int c0 = blockIdx.x * 32, r0 = blockIdx.y * 32;
    int tx = threadIdx.x & 31, ty = threadIdx.x >> 5;
    #pragma unroll
    for (int i = 0; i < 4; ++i)
        tile[ty + i * 8][tx] = src[(size_t)(r0 + ty + i * 8) * Cc + c0 + tx];
    __syncthreads();
    #pragma unroll
    for (int i = 0; i < 4; ++i)
        dst[(size_t)(c0 + ty + i * 8) * R + r0 + tx] = f2bf(tile[tx][ty + i * 8]);
}

// ---------------- fp32 GEMM (input proj, K=80) ----------------
#define BM 64
#define BN 64
#define BK 16

__global__ __launch_bounds__(256)
void gemm_f32_bias(const float* __restrict__ A, int lda,
                   const float* __restrict__ B,
                   const float* __restrict__ bias,
                   float* __restrict__ C, int ldc,
                   int M, int N, int K)
{
    __shared__ float As[BK][BM];
    __shared__ float Bs[BK][BN];
    const int bn = blockIdx.x * BN;
    const int bm = blockIdx.y * BM;
    const int tid = threadIdx.x;
    const int tx = tid & 15;
    const int ty = tid >> 4;
    const int ar = tid >> 2;
    const int ac = (tid & 3) * 4;
    const int br = tid >> 4;
    const int bc = (tid & 15) * 4;

    float acc[4][4] = {};

    for (int k0 = 0; k0 < K; k0 += BK) {
        float4 av = *(const float4*)&A[(bm + ar) * lda + k0 + ac];
        float4 bv = *(const float4*)&B[(k0 + br) * N + bn + bc];
        As[ac + 0][ar] = av.x;
        As[ac + 1][ar] = av.y;
        As[ac + 2][ar] = av.z;
        As[ac + 3][ar] = av.w;
        *(float4*)&Bs[br][bc] = bv;
        __syncthreads();
        #pragma unroll
        for (int kk = 0; kk < BK; ++kk) {
            float4 a = *(const float4*)&As[kk][ty * 4];
            float4 b = *(const float4*)&Bs[kk][tx * 4];
            float af[4] = {a.x, a.y, a.z, a.w};
            float bfv[4] = {b.x, b.y, b.z, b.w};
            #pragma unroll
            for (int i = 0; i < 4; ++i)
                #pragma unroll
                for (int j = 0; j < 4; ++j)
                    acc[i][j] = fmaf(af[i], bfv[j], acc[i][j]);
        }
        __syncthreads();
    }

    #pragma unroll
    for (int i = 0; i < 4; ++i) {
        int r = bm + ty * 4 + i;
        float* cp = &C[r * ldc + bn + tx * 4];
        float4 o;
        o.x = acc[i][0] + bias[bn + tx * 4 + 0];
        o.y = acc[i][1] + bias[bn + tx * 4 + 1];
        o.z = acc[i][2] + bias[bn + tx * 4 + 2];
        o.w = acc[i][3] + bias[bn + tx * 4 + 3];
        *(float4*)cp = o;
    }
}

// ---------------- LayerNorm -> bf16 ----------------
__global__ __launch_bounds__(256)
void ln_kernel(const float* __restrict__ x, const float* __restrict__ w,
               const float* __restrict__ b, unsigned short* __restrict__ out)
{
    int row = blockIdx.x;
    const float* xr = x + (size_t)row * DMODEL;
    int tid = threadIdx.x;
    float2 v = ((const float2*)xr)[tid];
    float s  = v.x + v.y;
    float sq = v.x * v.x + v.y * v.y;
    #pragma unroll
    for (int off = 32; off > 0; off >>= 1) {
        s  += __shfl_down(s, off);
        sq += __shfl_down(sq, off);
    }
    __shared__ float ss[4], ssq[4];
    if ((tid & 63) == 0) { ss[tid >> 6] = s; ssq[tid >> 6] = sq; }
    __syncthreads();
    s  = ss[0] + ss[1] + ss[2] + ss[3];
    sq = ssq[0] + ssq[1] + ssq[2] + ssq[3];
    float mu  = s * (1.f / DMODEL);
    float var = sq * (1.f / DMODEL) - mu * mu;
    float rs  = rsqrtf(var + 1e-5f);
    float2 wv = ((const float2*)w)[tid];
    float2 bv = ((const float2*)b)[tid];
    float o0 = (v.x - mu) * rs * wv.x + bv.x;
    float o1 = (v.y - mu) * rs * wv.y + bv.y;
    unsigned pack = (unsigned)f2bf(o0) | ((unsigned)f2bf(o1) << 16);
    ((unsigned*)(out + (size_t)row * DMODEL))[tid] = pack;
}

// ---------------- depthwise causal conv(3) + silu (bf16 in/out) ----------------
__global__ __launch_bounds__(256)
void conv_silu(const unsigned short* __restrict__ xz, const float* __restrict__ cw,
               const float* __restrict__ cb, unsigned short* __restrict__ ubf)
{
    int idx = blockIdx.x * 256 + threadIdx.x;
    int d   = idx & (DINNER - 1);
    int row = idx >> 10;
    int t   = row & (T_SEQ - 1);
    float acc = cb[d];
    #pragma unroll
    for (int k = 0; k < 3; ++k) {
        int tt = t - 2 + k;
        if (tt >= 0)
            acc += bf2f(xz[(size_t)(row - 2 + k) * (2 * DINNER) + d]) * cw[d * 3 + k];
    }
    float val = acc / (1.f + __expf(-acc));
    ubf[(size_t)row * DINNER + d] = f2bf(val);
}

// ---------------- chunked selective scan (channel-per-thread, bf16 streams) ----------------
__global__ __launch_bounds__(256)
void scan_phase1(const unsigned short* __restrict__ delta, const unsigned short* __restrict__ u,
                 const float* __restrict__ xdbl, const float* __restrict__ A_log,
                 unsigned short* __restrict__ hend, float* __restrict__ sd)
{
    __shared__ float Bsh[CLEN][DSTATE];
    int tid = threadIdx.x;
    int ch  = blockIdx.x * 256 + tid;
    int c   = blockIdx.y;
    int b   = ch >> 10;
    int d   = ch & (DINNER - 1);
    int row0 = b * T_SEQ + c * CLEN;
    if (tid < CLEN * DSTATE / 4) {
        int r = tid >> 2, col = (tid & 3) * 4;
        *(float4*)&Bsh[r][col] = *(const float4*)&xdbl[(size_t)(row0 + r) * 64 + DTRANK + col];
    }
    float A[DSTATE];
    const float* ap = A_log + (size_t)d * DSTATE;
    #pragma unroll
    for (int s = 0; s < DSTATE; ++s) A[s] = -__expf(ap[s]);
    __syncthreads();

    float h[DSTATE];
    #pragma unroll
    for (int s = 0; s < DSTATE; ++s) h[s] = 0.f;
    float sumd = 0.f;
    const unsigned short* dp = delta + (size_t)row0 * DINNER + d;
    const unsigned short* up = u     + (size_t)row0 * DINNER + d;
    for (int t = 0; t < CLEN; ++t) {
        float dlt = bf2f(dp[(size_t)t * DINNER]);
        float ut  = bf2f(up[(size_t)t * DINNER]);
        float du  = dlt * ut;
        sumd += dlt;
        #pragma unroll
        for (int s = 0; s < DSTATE; ++s)
            h[s] = __expf(dlt * A[s]) * h[s] + du * Bsh[t][s];
    }
    unsigned short* hp = hend + ((size_t)c * NCHAN + ch) * DSTATE;
    unsigned pk[8];
    #pragma unroll
    for (int i = 0; i < 8; ++i)
        pk[i] = (unsigned)f2bf(h[2 * i]) | ((unsigned)f2bf(h[2 * i + 1]) << 16);
    uint4 w0 = {pk[0], pk[1], pk[2], pk[3]};
    uint4 w1 = {pk[4], pk[5], pk[6], pk[7]};
    *(uint4*)hp = w0;
    *(uint4*)(hp + 8) = w1;
    sd[(size_t)c * NCHAN + ch] = sumd;
}

__global__ __launch_bounds__(256)
void scan_phase2(unsigned short* __restrict__ hbuf, const float* __restrict__ sd,
                 const float* __restrict__ A_log)
{
    int idx = blockIdx.x * 256 + threadIdx.x;   // < NCHAN*DSTATE
    int ch = idx >> 4, s = idx & 15;
    int d = ch & (DINNER - 1);
    float A = -__expf(A_log[(size_t)d * DSTATE + s]);
    float hrun = 0.f;
    for (int c = 0; c < NCH; ++c) {
        size_t o = (size_t)c * (NCHAN * DSTATE) + idx;
        float he  = bf2f(hbuf[o]);
        float sdv = sd[(size_t)c * NCHAN + ch];
        hbuf[o] = f2bf(hrun);
        hrun = __expf(A * sdv) * hrun + he;
    }
}

__global__ __launch_bounds__(256)
void scan_phase3(const unsigned short* __restrict__ delta, const unsigned short* __restrict__ u,
                 const float* __restrict__ xdbl, const float* __restrict__ A_log,
                 const float* __restrict__ Dp, const unsigned short* __restrict__ xz,
                 const unsigned short* __restrict__ hin, unsigned short* __restrict__ yy)
{
    __shared__ float BC[CLEN][2 * DSTATE];
    int tid = threadIdx.x;
    int ch  = blockIdx.x * 256 + tid;
    int c   = blockIdx.y;
    int b   = ch >> 10;
    int d   = ch & (DINNER - 1);
    int row0 = b * T_SEQ + c * CLEN;
    {
        int r = tid >> 3, col = (tid & 7) * 4;
        *(float4*)&BC[r][col] = *(const float4*)&xdbl[(size_t)(row0 + r) * 64 + DTRANK + col];
    }
    float A[DSTATE];
    const float* ap = A_log + (size_t)d * DSTATE;
    #pragma unroll
    for (int s = 0; s < DSTATE; ++s) A[s] = -__expf(ap[s]);
    float h[DSTATE];
    const unsigned short* hp = hin + ((size_t)c * NCHAN + ch) * DSTATE;
    uint4 p0 = *(const uint4*)hp;
    uint4 p1 = *(const uint4*)(hp + 8);
    unsigned pk[8] = {p0.x, p0.y, p0.z, p0.w, p1.x, p1.y, p1.z, p1.w};
    #pragma unroll
    for (int i = 0; i < 8; ++i) {
        h[2 * i]     = bf2f((unsigned short)(pk[i] & 0xffff));
        h[2 * i + 1] = bf2f((unsigned short)(pk[i] >> 16));
    }
    float Dval = Dp[d];
    __syncthreads();

    const unsigned short* dp = delta + (size_t)row0 * DINNER + d;
    const unsigned short* up = u     + (size_t)row0 * DINNER + d;
    const unsigned short* zp = xz    + (size_t)row0 * (2 * DINNER) + DINNER + d;
    unsigned short* yp = yy + (size_t)row0 * DINNER + d;
    for (int t = 0; t < CLEN; ++t) {
        float dlt = bf2f(dp[(size_t)t * DINNER]);
        float ut  = bf2f(up[(size_t)t * DINNER]);
        float du  = dlt * ut;
        float y0 = 0.f, y1 = 0.f;
        #pragma unroll
        for (int s = 0; s < DSTATE; s += 2) {
            h[s]     = __expf(dlt * A[s])     * h[s]     + du * BC[t][s];
            h[s + 1] = __expf(dlt * A[s + 1]) * h[s + 1] + du * BC[t][s + 1];
            y0 += h[s]     * BC[t][DSTATE + s];
            y1 += h[s + 1] * BC[t][DSTATE + s + 1];
        }
        float z = bf2f(zp[(size_t)t * (2 * DINNER)]);
        float sil = z / (1.f + __expf(-z));
        yp[(size_t)t * DINNER] = f2bf(((y0 + y1) + Dval * ut) * sil);
    }
}

// ---------------- masked mean pool (two-stage) ----------------
__global__ __launch_bounds__(512)
void pool_partial(const float* __restrict__ h, const int* __restrict__ lengths,
                  float* __restrict__ ppart)
{
    int b  = blockIdx.x;
    int ck = blockIdx.y;
    int dm = threadIdx.x;
    int len = lengths[b];
    int t0 = ck * (T_SEQ / PCHUNK);
    int t1 = t0 + (T_SEQ / PCHUNK);
    if (t1 > len) t1 = len;
    float acc = 0.f;
    for (int t = t0; t < t1; ++t)
        acc += h[((size_t)b * T_SEQ + t) * DMODEL + dm];
    ppart[((size_t)b * PCHUNK + ck) * DMODEL + dm] = acc;
}

__global__ __launch_bounds__(512)
void pool_final(const float* __restrict__ ppart, const int* __restrict__ lengths,
                float* __restrict__ pooled)
{
    int b  = blockIdx.x;
    int dm = threadIdx.x;
    float acc = 0.f;
    #pragma unroll
    for (int ck = 0; ck < PCHUNK; ++ck)
        acc += ppart[((size_t)b * PCHUNK + ck) * DMODEL + dm];
    pooled[b * DMODEL + dm] = acc / fmaxf((float)lengths[b], 1.f);
}

extern "C" void kernel_launch(void* const* d_in, const int* in_sizes, int n_in,
                              void* d_out, int out_size, void* d_ws, size_t ws_size,
                              hipStream_t stream)
{
    const float* x        = (const float*)d_in[0];
    const int*   lengths  = (const int*)d_in[1];
    const float* proj_w   = (const float*)d_in[2];
    const float* proj_b   = (const float*)d_in[3];
    const float* ln_w     = (const float*)d_in[4];
    const float* ln_b     = (const float*)d_in[5];
    const float* in_w     = (const float*)d_in[6];
    const float* conv_w   = (const float*)d_in[7];
    const float* conv_b   = (const float*)d_in[8];
    const float* xproj_w  = (const float*)d_in[9];
    const float* dtproj_w = (const float*)d_in[10];
    const float* dtproj_b = (const float*)d_in[11];
    const float* A_log    = (const float*)d_in[12];
    const float* Dp       = (const float*)d_in[13];
    const float* out_w    = (const float*)d_in[14];

    float* h      = (float*)d_out;                 // seq_out (8192x512)
    float* pooled = h + (size_t)MROWS * DMODEL;

    // --- workspace layout (bf16-first) ---
    unsigned short* xzb    = (unsigned short*)d_ws;                       // 8192*2048
    unsigned short* ubf    = xzb    + (size_t)MROWS * 2 * DINNER;         // 8192*1024
    unsigned short* deltab = ubf    + (size_t)MROWS * DINNER;             // 8192*1024
    unsigned short* hlnb   = deltab + (size_t)MROWS * DINNER;             // 8192*512
    unsigned short* yyb    = hlnb   + (size_t)MROWS * DMODEL;             // 8192*1024
    unsigned short* dtbf   = yyb    + (size_t)MROWS * DINNER;             // 8192*32
    unsigned short* inwT   = dtbf   + (size_t)MROWS * DTRANK;
    unsigned short* outwT  = inwT   + (size_t)NLAYER * DMODEL * 2 * DINNER;
    unsigned short* xprojT = outwT  + (size_t)NLAYER * DINNER * DMODEL;
    unsigned short* dtprojT= xprojT + (size_t)NLAYER * 64 * DINNER;
    unsigned short* hendb  = dtprojT+ (size_t)NLAYER * DTRANK * DINNER;   // 32*8192*16
    float* xdbl  = (float*)(hendb + (size_t)NCH * NCHAN * DSTATE);        // 8192*64
    float* sdbuf = xdbl  + (size_t)MROWS * 64;                            // 32*8192
    float* ppart = sdbuf + (size_t)NCH * NCHAN;                           // 8*16*512

    // Weight prep
    wconvT<<<dim3(2 * DINNER / 32, DMODEL / 32, NLAYER), 256, 0, stream>>>(in_w, inwT, DMODEL, 2 * DINNER);
    wconvT<<<dim3(DMODEL / 32, DINNER / 32, NLAYER), 256, 0, stream>>>(out_w, outwT, DINNER, DMODEL);
    wconvT<<<dim3(64 / 32, DINNER / 32, NLAYER), 256, 0, stream>>>(xproj_w, xprojT, DINNER, 64);
    wconvT<<<dim3(DINNER / 32, DTRANK / 32, NLAYER), 256, 0, stream>>>(dtproj_w, dtprojT, DTRANK, DINNER);

    // h = x @ proj_w + proj_b   (fp32; K=80)
    gemm_f32_bias<<<dim3(DMODEL / BN, MROWS / BM), 256, 0, stream>>>(
        x, 80, proj_w, proj_b, h, DMODEL, MROWS, DMODEL, 80);

    for (int l = 0; l < NLAYER; ++l) {
        ln_kernel<<<MROWS, 256, 0, stream>>>(h, ln_w + l * DMODEL, ln_b + l * DMODEL, hlnb);

        // xz = h_ln @ in_w   (MFMA -> bf16: M=8192, N=2048, K=512)
        gemm_mfma<0, true><<<dim3(2 * DINNER / 128, MROWS / 128), 256, 0, stream>>>(
            hlnb, inwT + (size_t)l * DMODEL * 2 * DINNER, nullptr, xzb, MROWS, 2 * DINNER, DMODEL);

        conv_silu<<<(MROWS * DINNER) / 256, 256, 0, stream>>>(
            xzb, conv_w + l * DINNER * 3, conv_b + l * DINNER, ubf);

        // x_dbl = u @ xproj_w  (MFMA: N=64, K=1024) + fused dt->bf16
        gemm_mfma_n64<<<dim3(1, MROWS / 128), 256, 0, stream>>>(
            ubf, xprojT + (size_t)l * 64 * DINNER, xdbl, dtbf, MROWS, DINNER);

        // delta = softplus(dt @ dtproj_w + dtproj_b)  (MFMA -> bf16: N=1024, K=32)
        gemm_mfma<2, true><<<dim3(DINNER / 128, MROWS / 128), 256, 0, stream>>>(
            dtbf, dtprojT + (size_t)l * DTRANK * DINNER, dtproj_b + l * DINNER,
            deltab, MROWS, DINNER, DTRANK);

        // chunked selective scan
        scan_phase1<<<dim3(NCHAN / 256, NCH), 256, 0, stream>>>(
            deltab, ubf, xdbl, A_log + (size_t)l * DINNER * DSTATE, hendb, sdbuf);
        scan_phase2<<<(NCHAN * DSTATE) / 256, 256, 0, stream>>>(
            hendb, sdbuf, A_log + (size_t)l * DINNER * DSTATE);
        scan_phase3<<<dim3(NCHAN / 256, NCH), 256, 0, stream>>>(
            deltab, ubf, xdbl, A_log + (size_t)l * DINNER * DSTATE, Dp + l * DINNER,
            xzb, hendb, yyb);

        // h += yy @ out_w   (MFMA residual fp32: N=512, K=1024)
        gemm_mfma<3, false><<<dim3(DMODEL / 128, MROWS / 128), 256, 0, stream>>>(
            yyb, outwT + (size_t)l * DINNER * DMODEL, nullptr, h, MROWS, DMODEL, DINNER);
    }

    pool_partial<<<dim3(BATCH, PCHUNK), 512, 0, stream>>>(h, lengths, ppart);
    pool_final<<<BATCH, 512, 0, stream>>>(ppart, lengths, pooled);
}

// Round 7
// 932.878 us; speedup vs baseline: 5.5637x; 1.0240x over previous
//
#include <hip/hip_runtime.h>
#include <math.h>

#define T_SEQ   1024
#define BATCH   8
#define DMODEL  512
#define DINNER  1024
#define DSTATE  16
#define DTRANK  32
#define NLAYER  4
#define MROWS   (BATCH * T_SEQ)   // 8192
#define NCH     32                // scan chunks
#define CLEN    (T_SEQ / NCH)     // 32
#define NCHAN   (BATCH * DINNER)  // 8192 channels
#define PCHUNK  16                // pool t-chunks

typedef float f32x4 __attribute__((ext_vector_type(4)));
typedef short s16x8 __attribute__((ext_vector_type(8)));

__device__ __forceinline__ unsigned short f2bf(float f) {
    unsigned u = __builtin_bit_cast(unsigned, f);
    u = (u + 0x7FFFu + ((u >> 16) & 1u)) >> 16;
    return (unsigned short)u;
}
__device__ __forceinline__ float bf2f(unsigned short v) {
    unsigned u = ((unsigned)v) << 16;
    return __builtin_bit_cast(float, u);
}

// ---------------- bf16 MFMA GEMM (128x128 tile) ----------------
// C[M,N] = A[M,K] bf16 @ B^T[N,K] bf16.
// EPI 0: plain store; 2: softplus(x + bias[n]); 3: fp32 C += acc (residual).
template<int EPI, bool BF16OUT>
__global__ __launch_bounds__(256)
void gemm_mfma(const unsigned short* __restrict__ A,
               const unsigned short* __restrict__ BT,
               const float* __restrict__ bias,
               void* __restrict__ Cv, int M, int N, int K)
{
    __shared__ __align__(16) unsigned short As[128 * 32];
    __shared__ __align__(16) unsigned short Bs[128 * 32];
    const int tid  = threadIdx.x;
    const int bn   = blockIdx.x * 128;
    const int bm   = blockIdx.y * 128;
    const int wave = tid >> 6;
    const int lane = tid & 63;
    const int wm = (wave >> 1) * 64;
    const int wn = (wave & 1) * 64;

    #define UNIT(row, kg) ((((row) << 2) | (kg)) ^ ((row) & 7))

    const int srow = tid >> 2;
    const int skg  = tid & 3;
    const int u0 = UNIT(srow, skg);
    const int u1 = UNIT(srow + 64, skg);

    const int r15 = lane & 15;
    const int kgl = lane >> 4;
    int aoff[4], boff[4];
    #pragma unroll
    for (int i = 0; i < 4; ++i) {
        aoff[i] = UNIT(wm + i * 16 + r15, kgl) * 8;
        boff[i] = UNIT(wn + i * 16 + r15, kgl) * 8;
    }

    const unsigned short* Ap0 = A  + (size_t)(bm + srow)      * K + skg * 8;
    const unsigned short* Ap1 = A  + (size_t)(bm + srow + 64) * K + skg * 8;
    const unsigned short* Bp0 = BT + (size_t)(bn + srow)      * K + skg * 8;
    const unsigned short* Bp1 = BT + (size_t)(bn + srow + 64) * K + skg * 8;

    f32x4 zero = {0.f, 0.f, 0.f, 0.f};
    f32x4 acc[4][4];
    #pragma unroll
    for (int i = 0; i < 4; ++i)
        #pragma unroll
        for (int j = 0; j < 4; ++j) acc[i][j] = zero;

    for (int k0 = 0; k0 < K; k0 += 32) {
        uint4 a0 = *(const uint4*)(Ap0 + k0);
        uint4 a1 = *(const uint4*)(Ap1 + k0);
        uint4 b0 = *(const uint4*)(Bp0 + k0);
        uint4 b1 = *(const uint4*)(Bp1 + k0);
        __syncthreads();
        *(uint4*)(As + u0 * 8) = a0;
        *(uint4*)(As + u1 * 8) = a1;
        *(uint4*)(Bs + u0 * 8) = b0;
        *(uint4*)(Bs + u1 * 8) = b1;
        __syncthreads();
        s16x8 fa[4], fb[4];
        #pragma unroll
        for (int i = 0; i < 4; ++i) {
            fa[i] = *(const s16x8*)(As + aoff[i]);
            fb[i] = *(const s16x8*)(Bs + boff[i]);
        }
        #pragma unroll
        for (int mi = 0; mi < 4; ++mi)
            #pragma unroll
            for (int ni = 0; ni < 4; ++ni)
                acc[mi][ni] = __builtin_amdgcn_mfma_f32_16x16x32_bf16(
                    fa[mi], fb[ni], acc[mi][ni], 0, 0, 0);
    }

    #pragma unroll
    for (int mi = 0; mi < 4; ++mi) {
        #pragma unroll
        for (int j = 0; j < 4; ++j) {
            int row = bm + wm + mi * 16 + kgl * 4 + j;
            #pragma unroll
            for (int ni = 0; ni < 4; ++ni) {
                float v = acc[mi][ni][j];
                int col = bn + wn + ni * 16 + r15;
                if (EPI == 2) {
                    v += bias[col];
                    v = (v > 20.f) ? v : log1pf(__expf(v));
                }
                if (BF16OUT) {
                    ((unsigned short*)Cv)[(size_t)row * N + col] = f2bf(v);
                } else {
                    float* cp = (float*)Cv + (size_t)row * N + col;
                    if (EPI == 3) v += *cp;
                    *cp = v;
                }
            }
        }
    }
    #undef UNIT
}

// ---------------- bf16 MFMA GEMM, N=64 (128x64 tile) ----------------
__global__ __launch_bounds__(256)
void gemm_mfma_n64(const unsigned short* __restrict__ A,
                   const unsigned short* __restrict__ BT,
                   float* __restrict__ C, unsigned short* __restrict__ dtb,
                   int M, int K)
{
    __shared__ __align__(16) unsigned short As[128 * 32];
    __shared__ __align__(16) unsigned short Bs[64 * 32];
    const int tid  = threadIdx.x;
    const int bm   = blockIdx.y * 128;
    const int wave = tid >> 6;
    const int lane = tid & 63;
    const int wm = wave * 32;

    #define UNIT(row, kg) ((((row) << 2) | (kg)) ^ ((row) & 7))
    const int srow = tid >> 2;
    const int skg  = tid & 3;
    const int u0 = UNIT(srow, skg);
    const int u1 = UNIT(srow + 64, skg);

    const int r15 = lane & 15;
    const int kgl = lane >> 4;
    int aoff[2], boff[4];
    #pragma unroll
    for (int i = 0; i < 2; ++i) aoff[i] = UNIT(wm + i * 16 + r15, kgl) * 8;
    #pragma unroll
    for (int i = 0; i < 4; ++i) boff[i] = UNIT(i * 16 + r15, kgl) * 8;

    const unsigned short* Ap0 = A  + (size_t)(bm + srow)      * K + skg * 8;
    const unsigned short* Ap1 = A  + (size_t)(bm + srow + 64) * K + skg * 8;
    const unsigned short* Bp  = BT + (size_t)srow             * K + skg * 8;

    f32x4 zero = {0.f, 0.f, 0.f, 0.f};
    f32x4 acc[2][4];
    #pragma unroll
    for (int i = 0; i < 2; ++i)
        #pragma unroll
        for (int j = 0; j < 4; ++j) acc[i][j] = zero;

    for (int k0 = 0; k0 < K; k0 += 32) {
        uint4 a0 = *(const uint4*)(Ap0 + k0);
        uint4 a1 = *(const uint4*)(Ap1 + k0);
        uint4 b0 = *(const uint4*)(Bp  + k0);
        __syncthreads();
        *(uint4*)(As + u0 * 8) = a0;
        *(uint4*)(As + u1 * 8) = a1;
        *(uint4*)(Bs + u0 * 8) = b0;
        __syncthreads();
        s16x8 fa[2], fb[4];
        #pragma unroll
        for (int i = 0; i < 2; ++i) fa[i] = *(const s16x8*)(As + aoff[i]);
        #pragma unroll
        for (int i = 0; i < 4; ++i) fb[i] = *(const s16x8*)(Bs + boff[i]);
        #pragma unroll
        for (int mi = 0; mi < 2; ++mi)
            #pragma unroll
            for (int ni = 0; ni < 4; ++ni)
                acc[mi][ni] = __builtin_amdgcn_mfma_f32_16x16x32_bf16(
                    fa[mi], fb[ni], acc[mi][ni], 0, 0, 0);
    }

    #pragma unroll
    for (int mi = 0; mi < 2; ++mi) {
        #pragma unroll
        for (int j = 0; j < 4; ++j) {
            int row = bm + wm + mi * 16 + kgl * 4 + j;
            float* cp = &C[(size_t)row * 64 + r15];
            #pragma unroll
            for (int ni = 0; ni < 4; ++ni) {
                float v = acc[mi][ni][j];
                cp[ni * 16] = v;
                if (ni < 2)
                    dtb[(size_t)row * DTRANK + ni * 16 + r15] = f2bf(v);
            }
        }
    }
    #undef UNIT
}

// ---------------- weight transpose + fp32->bf16 ----------------
__global__ __launch_bounds__(256)
void wconvT(const float* __restrict__ W, unsigned short* __restrict__ WT,
            int R, int Cc)
{
    int l = blockIdx.z;
    const float* src = W + (size_t)l * R * Cc;
    unsigned short* dst = WT + (size_t)l * R * Cc;
    __shared__ float tile[32][33];
    int c0 = blockIdx.x * 32, r0 = blockIdx.y * 32;
    int tx = threadIdx.x & 31, ty = threadIdx.x >> 5;
    #pragma unroll
    for (int i = 0; i < 4; ++i)
        tile[ty + i * 8][tx] = src[(size_t)(r0 + ty + i * 8) * Cc + c0 + tx];
    __syncthreads();
    #pragma unroll
    for (int i = 0; i < 4; ++i)
        dst[(size_t)(c0 + ty + i * 8) * R + r0 + tx] = f2bf(tile[tx][ty + i * 8]);
}

// ---------------- fp32 GEMM (input proj, K=80) ----------------
#define BM 64
#define BN 64
#define BK 16

__global__ __launch_bounds__(256)
void gemm_f32_bias(const float* __restrict__ A, int lda,
                   const float* __restrict__ B,
                   const float* __restrict__ bias,
                   float* __restrict__ C, int ldc,
                   int M, int N, int K)
{
    __shared__ float As[BK][BM];
    __shared__ float Bs[BK][BN];
    const int bn = blockIdx.x * BN;
    const int bm = blockIdx.y * BM;
    const int tid = threadIdx.x;
    const int tx = tid & 15;
    const int ty = tid >> 4;
    const int ar = tid >> 2;
    const int ac = (tid & 3) * 4;
    const int br = tid >> 4;
    const int bc = (tid & 15) * 4;

    float acc[4][4] = {};

    for (int k0 = 0; k0 < K; k0 += BK) {
        float4 av = *(const float4*)&A[(bm + ar) * lda + k0 + ac];
        float4 bv = *(const float4*)&B[(k0 + br) * N + bn + bc];
        As[ac + 0][ar] = av.x;
        As[ac + 1][ar] = av.y;
        As[ac + 2][ar] = av.z;
        As[ac + 3][ar] = av.w;
        *(float4*)&Bs[br][bc] = bv;
        __syncthreads();
        #pragma unroll
        for (int kk = 0; kk < BK; ++kk) {
            float4 a = *(const float4*)&As[kk][ty * 4];
            float4 b = *(const float4*)&Bs[kk][tx * 4];
            float af[4] = {a.x, a.y, a.z, a.w};
            float bfv[4] = {b.x, b.y, b.z, b.w};
            #pragma unroll
            for (int i = 0; i < 4; ++i)
                #pragma unroll
                for (int j = 0; j < 4; ++j)
                    acc[i][j] = fmaf(af[i], bfv[j], acc[i][j]);
        }
        __syncthreads();
    }

    #pragma unroll
    for (int i = 0; i < 4; ++i) {
        int r = bm + ty * 4 + i;
        float* cp = &C[r * ldc + bn + tx * 4];
        float4 o;
        o.x = acc[i][0] + bias[bn + tx * 4 + 0];
        o.y = acc[i][1] + bias[bn + tx * 4 + 1];
        o.z = acc[i][2] + bias[bn + tx * 4 + 2];
        o.w = acc[i][3] + bias[bn + tx * 4 + 3];
        *(float4*)cp = o;
    }
}

// ---------------- LayerNorm -> bf16 ----------------
__global__ __launch_bounds__(256)
void ln_kernel(const float* __restrict__ x, const float* __restrict__ w,
               const float* __restrict__ b, unsigned short* __restrict__ out)
{
    int row = blockIdx.x;
    const float* xr = x + (size_t)row * DMODEL;
    int tid = threadIdx.x;
    float2 v = ((const float2*)xr)[tid];
    float s  = v.x + v.y;
    float sq = v.x * v.x + v.y * v.y;
    #pragma unroll
    for (int off = 32; off > 0; off >>= 1) {
        s  += __shfl_down(s, off);
        sq += __shfl_down(sq, off);
    }
    __shared__ float ss[4], ssq[4];
    if ((tid & 63) == 0) { ss[tid >> 6] = s; ssq[tid >> 6] = sq; }
    __syncthreads();
    s  = ss[0] + ss[1] + ss[2] + ss[3];
    sq = ssq[0] + ssq[1] + ssq[2] + ssq[3];
    float mu  = s * (1.f / DMODEL);
    float var = sq * (1.f / DMODEL) - mu * mu;
    float rs  = rsqrtf(var + 1e-5f);
    float2 wv = ((const float2*)w)[tid];
    float2 bv = ((const float2*)b)[tid];
    float o0 = (v.x - mu) * rs * wv.x + bv.x;
    float o1 = (v.y - mu) * rs * wv.y + bv.y;
    unsigned pack = (unsigned)f2bf(o0) | ((unsigned)f2bf(o1) << 16);
    ((unsigned*)(out + (size_t)row * DMODEL))[tid] = pack;
}

// ---------------- depthwise causal conv(3) + silu, 8 channels/thread ----------------
__global__ __launch_bounds__(256)
void conv_silu(const unsigned short* __restrict__ xz, const float* __restrict__ cw,
               const float* __restrict__ cb, unsigned short* __restrict__ ubf)
{
    int idx = blockIdx.x * 256 + threadIdx.x;   // < MROWS*DINNER/8
    int dg  = (idx & 127) * 8;
    int row = idx >> 7;
    int t   = row & (T_SEQ - 1);

    float w[24];
    #pragma unroll
    for (int i = 0; i < 6; ++i)
        *(float4*)&w[i * 4] = *(const float4*)&cw[dg * 3 + i * 4];
    float acc[8];
    *(float4*)&acc[0] = *(const float4*)&cb[dg];
    *(float4*)&acc[4] = *(const float4*)&cb[dg + 4];

    #pragma unroll
    for (int k = 0; k < 3; ++k) {
        int tt = t - 2 + k;
        if (tt >= 0) {
            unsigned short vv[8];
            *(uint4*)vv = *(const uint4*)&xz[(size_t)(row - 2 + k) * (2 * DINNER) + dg];
            #pragma unroll
            for (int j = 0; j < 8; ++j)
                acc[j] = fmaf(bf2f(vv[j]), w[j * 3 + k], acc[j]);
        }
    }
    unsigned short ov[8];
    #pragma unroll
    for (int j = 0; j < 8; ++j) {
        float val = acc[j] / (1.f + __expf(-acc[j]));
        ov[j] = f2bf(val);
    }
    *(uint4*)&ubf[(size_t)row * DINNER + dg] = *(uint4*)ov;
}

// ---------------- chunked selective scan (channel-per-thread, LDS-staged) ----------------
// Block: 256 channels (same batch) x one chunk. Cooperative uint4 staging.
__global__ __launch_bounds__(256)
void scan_phase1(const unsigned short* __restrict__ delta, const unsigned short* __restrict__ u,
                 const float* __restrict__ xdbl, const float* __restrict__ A_log,
                 unsigned short* __restrict__ hend, float* __restrict__ sd)
{
    __shared__ unsigned short dl[CLEN][256];
    __shared__ unsigned short ul[CLEN][256];
    __shared__ float Bsh[CLEN][DSTATE];
    int tid = threadIdx.x;
    int b   = (blockIdx.x * 256) >> 10;
    int d0  = (blockIdx.x * 256) & (DINNER - 1);
    int ch  = blockIdx.x * 256 + tid;
    int d   = d0 + tid;
    int c   = blockIdx.y;
    int row0 = b * T_SEQ + c * CLEN;

    if (tid < CLEN * DSTATE / 4) {
        int r = tid >> 2, col = (tid & 3) * 4;
        *(float4*)&Bsh[r][col] = *(const float4*)&xdbl[(size_t)(row0 + r) * 64 + DTRANK + col];
    }
    {
        int rbase = tid >> 5, col = (tid & 31) * 8;
        #pragma unroll
        for (int rr = 0; rr < 4; ++rr) {
            int r = rr * 8 + rbase;
            *(uint4*)&dl[r][col] = *(const uint4*)&delta[(size_t)(row0 + r) * DINNER + d0 + col];
            *(uint4*)&ul[r][col] = *(const uint4*)&u[(size_t)(row0 + r) * DINNER + d0 + col];
        }
    }
    float A[DSTATE];
    const float* ap = A_log + (size_t)d * DSTATE;
    #pragma unroll
    for (int s = 0; s < DSTATE; ++s) A[s] = -__expf(ap[s]);
    __syncthreads();

    float h[DSTATE];
    #pragma unroll
    for (int s = 0; s < DSTATE; ++s) h[s] = 0.f;
    float sumd = 0.f;
    for (int t = 0; t < CLEN; ++t) {
        float dlt = bf2f(dl[t][tid]);
        float ut  = bf2f(ul[t][tid]);
        float du  = dlt * ut;
        sumd += dlt;
        #pragma unroll
        for (int s = 0; s < DSTATE; ++s)
            h[s] = __expf(dlt * A[s]) * h[s] + du * Bsh[t][s];
    }
    unsigned short* hp = hend + ((size_t)c * NCHAN + ch) * DSTATE;
    unsigned pk[8];
    #pragma unroll
    for (int i = 0; i < 8; ++i)
        pk[i] = (unsigned)f2bf(h[2 * i]) | ((unsigned)f2bf(h[2 * i + 1]) << 16);
    uint4 w0 = {pk[0], pk[1], pk[2], pk[3]};
    uint4 w1 = {pk[4], pk[5], pk[6], pk[7]};
    *(uint4*)hp = w0;
    *(uint4*)(hp + 8) = w1;
    sd[(size_t)c * NCHAN + ch] = sumd;
}

__global__ __launch_bounds__(256)
void scan_phase2(unsigned short* __restrict__ hbuf, const float* __restrict__ sd,
                 const float* __restrict__ A_log)
{
    int idx = blockIdx.x * 256 + threadIdx.x;
    int ch = idx >> 4, s = idx & 15;
    int d = ch & (DINNER - 1);
    float A = -__expf(A_log[(size_t)d * DSTATE + s]);
    float hrun = 0.f;
    for (int c = 0; c < NCH; ++c) {
        size_t o = (size_t)c * (NCHAN * DSTATE) + idx;
        float he  = bf2f(hbuf[o]);
        float sdv = sd[(size_t)c * NCHAN + ch];
        hbuf[o] = f2bf(hrun);
        hrun = __expf(A * sdv) * hrun + he;
    }
}

__global__ __launch_bounds__(256)
void scan_phase3(const unsigned short* __restrict__ delta, const unsigned short* __restrict__ u,
                 const float* __restrict__ xdbl, const float* __restrict__ A_log,
                 const float* __restrict__ Dp, const unsigned short* __restrict__ xz,
                 const unsigned short* __restrict__ hin, unsigned short* __restrict__ yy)
{
    __shared__ unsigned short dl[CLEN][256];
    __shared__ unsigned short ul[CLEN][256];
    __shared__ unsigned short zl[CLEN][256];
    __shared__ float BC[CLEN][2 * DSTATE];
    int tid = threadIdx.x;
    int b   = (blockIdx.x * 256) >> 10;
    int d0  = (blockIdx.x * 256) & (DINNER - 1);
    int ch  = blockIdx.x * 256 + tid;
    int d   = d0 + tid;
    int c   = blockIdx.y;
    int row0 = b * T_SEQ + c * CLEN;
    {
        int r = tid >> 3, col = (tid & 7) * 4;
        *(float4*)&BC[r][col] = *(const float4*)&xdbl[(size_t)(row0 + r) * 64 + DTRANK + col];
    }
    {
        int rbase = tid >> 5, col = (tid & 31) * 8;
        #pragma unroll
        for (int rr = 0; rr < 4; ++rr) {
            int r = rr * 8 + rbase;
            *(uint4*)&dl[r][col] = *(const uint4*)&delta[(size_t)(row0 + r) * DINNER + d0 + col];
            *(uint4*)&ul[r][col] = *(const uint4*)&u[(size_t)(row0 + r) * DINNER + d0 + col];
            *(uint4*)&zl[r][col] = *(const uint4*)&xz[(size_t)(row0 + r) * (2 * DINNER) + DINNER + d0 + col];
        }
    }
    float A[DSTATE];
    const float* ap = A_log + (size_t)d * DSTATE;
    #pragma unroll
    for (int s = 0; s < DSTATE; ++s) A[s] = -__expf(ap[s]);
    float h[DSTATE];
    const unsigned short* hp = hin + ((size_t)c * NCHAN + ch) * DSTATE;
    uint4 p0 = *(const uint4*)hp;
    uint4 p1 = *(const uint4*)(hp + 8);
    unsigned pk[8] = {p0.x, p0.y, p0.z, p0.w, p1.x, p1.y, p1.z, p1.w};
    #pragma unroll
    for (int i = 0; i < 8; ++i) {
        h[2 * i]     = bf2f((unsigned short)(pk[i] & 0xffff));
        h[2 * i + 1] = bf2f((unsigned short)(pk[i] >> 16));
    }
    float Dval = Dp[d];
    __syncthreads();

    unsigned short* yp = yy + (size_t)row0 * DINNER + d;
    for (int t = 0; t < CLEN; ++t) {
        float dlt = bf2f(dl[t][tid]);
        float ut  = bf2f(ul[t][tid]);
        float du  = dlt * ut;
        float y0 = 0.f, y1 = 0.f;
        #pragma unroll
        for (int s = 0; s < DSTATE; s += 2) {
            h[s]     = __expf(dlt * A[s])     * h[s]     + du * BC[t][s];
            h[s + 1] = __expf(dlt * A[s + 1]) * h[s + 1] + du * BC[t][s + 1];
            y0 += h[s]     * BC[t][DSTATE + s];
            y1 += h[s + 1] * BC[t][DSTATE + s + 1];
        }
        float z = bf2f(zl[t][tid]);
        float sil = z / (1.f + __expf(-z));
        yp[(size_t)t * DINNER] = f2bf(((y0 + y1) + Dval * ut) * sil);
    }
}

// ---------------- masked mean pool (two-stage) ----------------
__global__ __launch_bounds__(512)
void pool_partial(const float* __restrict__ h, const int* __restrict__ lengths,
                  float* __restrict__ ppart)
{
    int b  = blockIdx.x;
    int ck = blockIdx.y;
    int dm = threadIdx.x;
    int len = lengths[b];
    int t0 = ck * (T_SEQ / PCHUNK);
    int t1 = t0 + (T_SEQ / PCHUNK);
    if (t1 > len) t1 = len;
    float acc = 0.f;
    for (int t = t0; t < t1; ++t)
        acc += h[((size_t)b * T_SEQ + t) * DMODEL + dm];
    ppart[((size_t)b * PCHUNK + ck) * DMODEL + dm] = acc;
}

__global__ __launch_bounds__(512)
void pool_final(const float* __restrict__ ppart, const int* __restrict__ lengths,
                float* __restrict__ pooled)
{
    int b  = blockIdx.x;
    int dm = threadIdx.x;
    float acc = 0.f;
    #pragma unroll
    for (int ck = 0; ck < PCHUNK; ++ck)
        acc += ppart[((size_t)b * PCHUNK + ck) * DMODEL + dm];
    pooled[b * DMODEL + dm] = acc / fmaxf((float)lengths[b], 1.f);
}

extern "C" void kernel_launch(void* const* d_in, const int* in_sizes, int n_in,
                              void* d_out, int out_size, void* d_ws, size_t ws_size,
                              hipStream_t stream)
{
    const float* x        = (const float*)d_in[0];
    const int*   lengths  = (const int*)d_in[1];
    const float* proj_w   = (const float*)d_in[2];
    const float* proj_b   = (const float*)d_in[3];
    const float* ln_w     = (const float*)d_in[4];
    const float* ln_b     = (const float*)d_in[5];
    const float* in_w     = (const float*)d_in[6];
    const float* conv_w   = (const float*)d_in[7];
    const float* conv_b   = (const float*)d_in[8];
    const float* xproj_w  = (const float*)d_in[9];
    const float* dtproj_w = (const float*)d_in[10];
    const float* dtproj_b = (const float*)d_in[11];
    const float* A_log    = (const float*)d_in[12];
    const float* Dp       = (const float*)d_in[13];
    const float* out_w    = (const float*)d_in[14];

    float* h      = (float*)d_out;                 // seq_out (8192x512)
    float* pooled = h + (size_t)MROWS * DMODEL;

    // --- workspace layout (bf16-first) ---
    unsigned short* xzb    = (unsigned short*)d_ws;                       // 8192*2048
    unsigned short* ubf    = xzb    + (size_t)MROWS * 2 * DINNER;         // 8192*1024
    unsigned short* deltab = ubf    + (size_t)MROWS * DINNER;             // 8192*1024
    unsigned short* hlnb   = deltab + (size_t)MROWS * DINNER;             // 8192*512
    unsigned short* yyb    = hlnb   + (size_t)MROWS * DMODEL;             // 8192*1024
    unsigned short* dtbf   = yyb    + (size_t)MROWS * DINNER;             // 8192*32
    unsigned short* inwT   = dtbf   + (size_t)MROWS * DTRANK;
    unsigned short* outwT  = inwT   + (size_t)NLAYER * DMODEL * 2 * DINNER;
    unsigned short* xprojT = outwT  + (size_t)NLAYER * DINNER * DMODEL;
    unsigned short* dtprojT= xprojT + (size_t)NLAYER * 64 * DINNER;
    unsigned short* hendb  = dtprojT+ (size_t)NLAYER * DTRANK * DINNER;   // 32*8192*16
    float* xdbl  = (float*)(hendb + (size_t)NCH * NCHAN * DSTATE);        // 8192*64
    float* sdbuf = xdbl  + (size_t)MROWS * 64;                            // 32*8192
    float* ppart = sdbuf + (size_t)NCH * NCHAN;                           // 8*16*512

    // Weight prep
    wconvT<<<dim3(2 * DINNER / 32, DMODEL / 32, NLAYER), 256, 0, stream>>>(in_w, inwT, DMODEL, 2 * DINNER);
    wconvT<<<dim3(DMODEL / 32, DINNER / 32, NLAYER), 256, 0, stream>>>(out_w, outwT, DINNER, DMODEL);
    wconvT<<<dim3(64 / 32, DINNER / 32, NLAYER), 256, 0, stream>>>(xproj_w, xprojT, DINNER, 64);
    wconvT<<<dim3(DINNER / 32, DTRANK / 32, NLAYER), 256, 0, stream>>>(dtproj_w, dtprojT, DTRANK, DINNER);

    // h = x @ proj_w + proj_b   (fp32; K=80)
    gemm_f32_bias<<<dim3(DMODEL / BN, MROWS / BM), 256, 0, stream>>>(
        x, 80, proj_w, proj_b, h, DMODEL, MROWS, DMODEL, 80);

    for (int l = 0; l < NLAYER; ++l) {
        ln_kernel<<<MROWS, 256, 0, stream>>>(h, ln_w + l * DMODEL, ln_b + l * DMODEL, hlnb);

        // xz = h_ln @ in_w   (MFMA -> bf16)
        gemm_mfma<0, true><<<dim3(2 * DINNER / 128, MROWS / 128), 256, 0, stream>>>(
            hlnb, inwT + (size_t)l * DMODEL * 2 * DINNER, nullptr, xzb, MROWS, 2 * DINNER, DMODEL);

        conv_silu<<<(MROWS * DINNER / 8) / 256, 256, 0, stream>>>(
            xzb, conv_w + l * DINNER * 3, conv_b + l * DINNER, ubf);

        // x_dbl = u @ xproj_w  (MFMA) + fused dt->bf16
        gemm_mfma_n64<<<dim3(1, MROWS / 128), 256, 0, stream>>>(
            ubf, xprojT + (size_t)l * 64 * DINNER, xdbl, dtbf, MROWS, DINNER);

        // delta = softplus(dt @ dtproj_w + dtproj_b)  (MFMA -> bf16)
        gemm_mfma<2, true><<<dim3(DINNER / 128, MROWS / 128), 256, 0, stream>>>(
            dtbf, dtprojT + (size_t)l * DTRANK * DINNER, dtproj_b + l * DINNER,
            deltab, MROWS, DINNER, DTRANK);

        // chunked selective scan (LDS-staged)
        scan_phase1<<<dim3(NCHAN / 256, NCH), 256, 0, stream>>>(
            deltab, ubf, xdbl, A_log + (size_t)l * DINNER * DSTATE, hendb, sdbuf);
        scan_phase2<<<(NCHAN * DSTATE) / 256, 256, 0, stream>>>(
            hendb, sdbuf, A_log + (size_t)l * DINNER * DSTATE);
        scan_phase3<<<dim3(NCHAN / 256, NCH), 256, 0, stream>>>(
            deltab, ubf, xdbl, A_log + (size_t)l * DINNER * DSTATE, Dp + l * DINNER,
            xzb, hendb, yyb);

        // h += yy @ out_w   (MFMA residual fp32)
        gemm_mfma<3, false><<<dim3(DMODEL / 128, MROWS / 128), 256, 0, stream>>>(
            yyb, outwT + (size_t)l * DINNER * DMODEL, nullptr, h, MROWS, DMODEL, DINNER);
    }

    pool_partial<<<dim3(BATCH, PCHUNK), 512, 0, stream>>>(h, lengths, ppart);
    pool_final<<<BATCH, 512, 0, stream>>>(ppart, lengths, pooled);
}